// Round 6
// baseline (621.545 us; speedup 1.0000x reference)
//
#include <hip/hip_runtime.h>
#include <math.h>

// ---------------------------------------------------------------------------
// MixedAttention: H=W=256, C=192, HEADS=6, NA: K=7 DIL=2 hd=32,
// stripe: WS=8 AWS=4 hs=16, 1024 windows.
// R13: na_attn phase-split. R12 counters: 88us, HBM 9%, VALU 32%, Mfma 4.9%
// -> ~55us pure stall from the per-row serial chain (Kload->MFMA->exp->LDS->
// read->Vload->MFMA)x7. Now: phase1 = all 14 K-loads + 14 QK MFMAs
// (independent, pipelined); phase2 = all 56 exps + P pack -> LDS (7-row
// buffer, 20-word row stride: <=2-way banks, 16B aligned); phase3 = 7x
// {ds_read_b128 + 2 VT loads + 2 PV MFMAs}, two accumulator pairs to halve
// the serial accum chain. Same math up to fp32 reassociation of PV accum.
// ---------------------------------------------------------------------------

typedef unsigned short bf16_t;
typedef __attribute__((ext_vector_type(8))) short short8;   // MFMA A/B frag (8 bf16)
typedef __attribute__((ext_vector_type(4))) float f32x4;    // MFMA C/D frag

__device__ inline float bf2f(bf16_t v) { return __uint_as_float((unsigned)v << 16); }
__device__ inline bf16_t f2bf(float f) {
    unsigned u = __float_as_uint(f);
    unsigned r = (u + 0x7fffu + ((u >> 16) & 1u)) >> 16;   // RNE, finite inputs
    return (bf16_t)r;
}
__device__ inline float cvt(float v) { return v; }
__device__ inline float cvt(bf16_t v) { return bf2f(v); }
__device__ inline void sto(float* p, float v) { *p = v; }
__device__ inline void sto(bf16_t* p, float v) { *p = f2bf(v); }

// load 8 consecutive bf16 (16B aligned) -> 8 floats
__device__ inline void ld_bf8(const bf16_t* p, float* d) {
    uint4 r = *(const uint4*)p;
    d[0] = __uint_as_float(r.x << 16); d[1] = __uint_as_float(r.x & 0xffff0000u);
    d[2] = __uint_as_float(r.y << 16); d[3] = __uint_as_float(r.y & 0xffff0000u);
    d[4] = __uint_as_float(r.z << 16); d[5] = __uint_as_float(r.z & 0xffff0000u);
    d[6] = __uint_as_float(r.w << 16); d[7] = __uint_as_float(r.w & 0xffff0000u);
}
__device__ inline unsigned pk2(float a, float b) {
    return (unsigned)f2bf(a) | ((unsigned)f2bf(b) << 16);
}

// ---------------------------------------------------------------------------
// MFMA GEMM: C[M,N] = A[M,K]bf16 @ Bt[N,K]^T + bias. Tile 128x96, 4 waves,
// each wave 64x48 = 4x3 16x16 frags, K=192 fully unrolled, no LDS.
// 1D grid (multiple of 8) with bijective XCD chunk swizzle; NCOL = column
// tiles per row so each XCD owns contiguous rows x all cols (A L2 reuse).
// NA=1: scatter-store into parity-split head planes:
//   ((which*6+h)*65536 + par*16384 + pixin)*32 + d   (Q,K,V all plane-major)
// ---------------------------------------------------------------------------
template <int KD, int NA, int NCOL, typename TO>
__global__ __launch_bounds__(256) void mfma_gemm_k(
    const bf16_t* __restrict__ A, const bf16_t* __restrict__ Bt,
    const float* __restrict__ bias, TO* __restrict__ C,
    int lda, int ldb, int ldc)
{
    const int bid  = blockIdx.x;
    const int work = (bid & 7) * (gridDim.x >> 3) + (bid >> 3);
    const int brow = work / NCOL;
    const int bcol = work - brow * NCOL;

    const int t = threadIdx.x;
    const int lane = t & 63, wave = t >> 6;
    const int wr = wave >> 1, wc = wave & 1;
    const int m0 = brow * 128 + wr * 64;
    const int n0 = bcol * 96 + wc * 48;
    const int lm = lane & 15;
    const int q  = lane >> 4;

    f32x4 acc[4][3] = {};
    const bf16_t* ap = A + (size_t)(m0 + lm) * lda + q * 8;
    const bf16_t* bp = Bt + (size_t)(n0 + lm) * ldb + q * 8;

#pragma unroll
    for (int k0 = 0; k0 < KD; k0 += 32) {
        short8 af[4], bf[3];
#pragma unroll
        for (int mi = 0; mi < 4; mi++)
            af[mi] = *(const short8*)(ap + (size_t)(mi * 16) * lda + k0);
#pragma unroll
        for (int ni = 0; ni < 3; ni++)
            bf[ni] = *(const short8*)(bp + (size_t)(ni * 16) * ldb + k0);
#pragma unroll
        for (int mi = 0; mi < 4; mi++)
#pragma unroll
            for (int ni = 0; ni < 3; ni++)
                acc[mi][ni] = __builtin_amdgcn_mfma_f32_16x16x32_bf16(
                    af[mi], bf[ni], acc[mi][ni], 0, 0, 0);
    }

#pragma unroll
    for (int mi = 0; mi < 4; mi++) {
#pragma unroll
        for (int ni = 0; ni < 3; ni++) {
            int col = n0 + ni * 16 + lm;
            float bv = bias[col];
            if (NA) {
                int which = col / 192;
                int hh = (col % 192) / 32;
                int d  = col % 32;
                size_t pbase = ((size_t)which * 6 + hh) * 2097152 + d;
#pragma unroll
                for (int r = 0; r < 4; r++) {
                    int row = m0 + mi * 16 + q * 4 + r;
                    int ii = row >> 8, jj = row & 255;
                    int par = ((ii & 1) << 1) | (jj & 1);
                    int pixin = (ii >> 1) * 128 + (jj >> 1);
                    sto(&C[pbase + ((size_t)(par * 16384 + pixin) << 5)],
                        acc[mi][ni][r] + bv);
                }
            } else {
#pragma unroll
                for (int r = 0; r < 4; r++) {
                    int row = m0 + mi * 16 + q * 4 + r;
                    sto(&C[(size_t)row * ldc + col], acc[mi][ni][r] + bv);
                }
            }
        }
    }
}

// V planes ([pix][d]) -> VT planes ([d][pix]) via LDS tile transpose.
// grid 3072 = 24 (h,par) x 128 tiles of 128 px; block 256.
__global__ __launch_bounds__(256) void vtpose_k(
    const bf16_t* __restrict__ nap, bf16_t* __restrict__ vt)
{
    __shared__ unsigned short tl[32][144];   // [d][px], pad 16 px
    const int b = blockIdx.x;
    const int z = b >> 7;            // h*4+par
    const int tile = b & 127;
    const int h = z >> 2, par = z & 3;
    const int pix0 = tile << 7;

    const bf16_t* sp = nap + (size_t)(12 + h) * 2097152
                     + ((size_t)(par * 16384 + pix0) << 5);
    const int t = threadIdx.x;
    {
        const int px = t & 127, half = t >> 7;        // half: d 0..15 / 16..31
        uint4 r0 = *(const uint4*)(sp + px * 32 + half * 16);
        uint4 r1 = *(const uint4*)(sp + px * 32 + half * 16 + 8);
        const unsigned short* u0 = (const unsigned short*)&r0;
        const unsigned short* u1 = (const unsigned short*)&r1;
#pragma unroll
        for (int i = 0; i < 8; i++) tl[half * 16 + i][px] = u0[i];
#pragma unroll
        for (int i = 0; i < 8; i++) tl[half * 16 + 8 + i][px] = u1[i];
    }
    __syncthreads();
    {
        const int d = t >> 3, g = t & 7;              // 32 d x 8 groups of 16 px
        unsigned short buf[16];
#pragma unroll
        for (int i = 0; i < 16; i++) buf[i] = tl[d][g * 16 + i];
        bf16_t* dp = vt + ((size_t)z << 19) + ((size_t)d << 14) + pix0 + g * 16;
        *(uint4*)dp = *(uint4*)buf;
        *(uint4*)(dp + 8) = *(uint4*)(buf + 8);
    }
}

// x fp32 -> bf16, 8 elems/thread
__global__ __launch_bounds__(256) void cvt_bf16_k(
    const float* __restrict__ src, bf16_t* __restrict__ dst, int n8)
{
    int tid = blockIdx.x * 256 + threadIdx.x;
    if (tid >= n8) return;
    float4 a = ((const float4*)src)[tid * 2];
    float4 b = ((const float4*)src)[tid * 2 + 1];
    uint4 o;
    o.x = pk2(a.x, a.y); o.y = pk2(a.z, a.w);
    o.z = pk2(b.x, b.y); o.w = pk2(b.z, b.w);
    ((uint4*)dst)[tid] = o;
}

// Wt[n*Kd + k] = (bf16) W[k*ld + coloff + n]   (transpose + convert)
__global__ __launch_bounds__(256) void tcvt_k(
    const float* __restrict__ W, bf16_t* __restrict__ Wt,
    int Kd, int N, int ld, int coloff)
{
    int tid = blockIdx.x * 256 + threadIdx.x;
    if (tid >= Kd * N) return;
    int k = tid % Kd, n = tid / Kd;
    Wt[tid] = f2bf(W[(size_t)k * ld + coloff + n]);
}

// qkv_wT[j*192 + k] = qkv_w[k*576 + j], j < 288
__global__ __launch_bounds__(256) void tpose_qkvw_k(
    const float* __restrict__ W, float* __restrict__ WT)
{
    int tid = blockIdx.x * 256 + threadIdx.x;
    if (tid >= 288 * 192) return;
    int k = tid % 192, j = tid / 192;
    WT[tid] = W[(size_t)k * 576 + j];
}

// Wna_t[n*192 + k] = (bf16) sum_j qkv_wT[j,k] * na_qkv_w[j,n], j<288
__global__ __launch_bounds__(256) void fold_wna_t_k(
    const float* __restrict__ qkv_wT, const float* __restrict__ na_qkv_w,
    bf16_t* __restrict__ Wna_t)
{
    int tid = blockIdx.x * 256 + threadIdx.x;
    if (tid >= 576 * 192) return;
    int k = tid % 192, n = tid / 192;
    float acc = 0.f;
    for (int j = 0; j < 288; j++)
        acc += qkv_wT[j * 192 + k] * na_qkv_w[j * 576 + n];
    Wna_t[tid] = f2bf(acc);
}

__global__ __launch_bounds__(256) void fold_bna_k(
    const float* __restrict__ qkv_b, const float* __restrict__ na_qkv_w,
    const float* __restrict__ na_qkv_b, float* __restrict__ bna)
{
    int j = blockIdx.x * 256 + threadIdx.x;
    if (j >= 576) return;
    float acc = na_qkv_b[j];
    for (int k = 0; k < 288; k++)
        acc += qkv_b[k] * na_qkv_w[k * 576 + j];
    bna[j] = acc;
}

// bt[t,h] = (relu(table(225,2) @ w1 + b1) @ w2)[t,h]
__global__ __launch_bounds__(256) void cpb_k(
    const float* __restrict__ table, const float* __restrict__ w1,
    const float* __restrict__ b1, const float* __restrict__ w2,
    float* __restrict__ bt)
{
    int tid = blockIdx.x * 256 + threadIdx.x;
    if (tid >= 225 * 6) return;
    int h = tid % 6, t = tid / 6;
    float t0 = table[t * 2], t1 = table[t * 2 + 1];
    float acc = 0.f;
    for (int m = 0; m < 512; m++) {
        float hv = t0 * w1[m] + t1 * w1[512 + m] + b1[m];
        hv = fmaxf(hv, 0.f);
        acc += hv * w2[m * 6 + h];
    }
    bt[tid] = acc;
}

// b2p[h*1024 + n1*16 + m] = 16*sigmoid(bt[idx[n1*16+m]*6 + h])  (attn2)
__global__ __launch_bounds__(256) void sigb_k(
    const float* __restrict__ bt, const int* __restrict__ idx,
    float* __restrict__ bp)
{
    int tid = blockIdx.x * 256 + threadIdx.x;
    if (tid >= 6144) return;
    int h = tid >> 10, p = tid & 1023;
    bp[tid] = 16.0f / (1.0f + __expf(-bt[idx[p] * 6 + h]));
}

// b1pT[h*1024 + m*16 + n2] = 16*sigmoid(bt[idx[n2*64+m]*6 + h])  (attn1)
__global__ __launch_bounds__(256) void sigb1T_k(
    const float* __restrict__ bt, const int* __restrict__ idx,
    float* __restrict__ bp)
{
    int tid = blockIdx.x * 256 + threadIdx.x;
    if (tid >= 6144) return;
    int h = tid >> 10, p = tid & 1023;
    int m = p >> 4, n2 = p & 15;
    bp[tid] = 16.0f / (1.0f + __expf(-bt[idx[n2 * 64 + m] * 6 + h]));
}

// legacy fp32 tiled GEMM (kept for the small anchor-pointwise GEMM)
#define BM 64
#define BN 64
#define BKK 16
template <typename TA, typename TO>
__global__ __launch_bounds__(256) void gemm_k(
    const TA* __restrict__ A, const float* __restrict__ B,
    const float* __restrict__ bias, TO* __restrict__ C,
    int M, int N, int Kd, int lda, int ldb, int ldc)
{
    __shared__ float As[BKK][BM + 1];
    __shared__ float Bs[BKK][BN + 1];
    const int t  = threadIdx.x;
    const int tx = t & 15, ty = t >> 4;
    const int m0 = blockIdx.y * BM, n0 = blockIdx.x * BN;
    float acc[4][4] = {};

    for (int k0 = 0; k0 < Kd; k0 += BKK) {
#pragma unroll
        for (int i = 0; i < 4; i++) {
            int m = (t >> 4) + i * 16;
            int k = t & 15;
            int gm = m0 + m, gk = k0 + k;
            As[k][m] = (gm < M && gk < Kd) ? cvt(A[(size_t)gm * lda + gk]) : 0.f;
        }
#pragma unroll
        for (int i = 0; i < 4; i++) {
            int k = (t >> 6) + i * 4;
            int n = t & 63;
            int gk = k0 + k, gn = n0 + n;
            Bs[k][n] = (gk < Kd && gn < N) ? B[(size_t)gk * ldb + gn] : 0.f;
        }
        __syncthreads();
#pragma unroll
        for (int k = 0; k < BKK; k++) {
            float a[4], b[4];
#pragma unroll
            for (int i = 0; i < 4; i++) a[i] = As[k][ty * 4 + i];
#pragma unroll
            for (int j = 0; j < 4; j++) b[j] = Bs[k][tx * 4 + j];
#pragma unroll
            for (int i = 0; i < 4; i++)
#pragma unroll
                for (int j = 0; j < 4; j++) acc[i][j] += a[i] * b[j];
        }
        __syncthreads();
    }
#pragma unroll
    for (int i = 0; i < 4; i++) {
        int gm = m0 + ty * 4 + i;
        if (gm >= M) continue;
#pragma unroll
        for (int j = 0; j < 4; j++) {
            int gn = n0 + tx * 4 + j;
            if (gn >= N) continue;
            sto(&C[(size_t)gm * ldc + gn], acc[i][j] + bias[gn]);
        }
    }
}

// Depthwise 3x3 stride-2 pad-1 on x (256,256,192) -> adw (128,128,192) fp32
__global__ __launch_bounds__(256) void dwconv_k(
    const float* __restrict__ x, const float* __restrict__ w,
    const float* __restrict__ b, float* __restrict__ adw)
{
    int tid = blockIdx.x * 256 + threadIdx.x;
    if (tid >= 16384 * 48) return;
    int c4 = tid % 48;
    int p = tid / 48;
    int ow = p & 127, oh = p >> 7;
    int c = c4 * 4;
    float4 s = *(const float4*)(b + c);
#pragma unroll
    for (int kh = 0; kh < 3; kh++) {
        int ih = oh * 2 - 1 + kh;
        if (ih < 0 || ih >= 256) continue;
#pragma unroll
        for (int kw = 0; kw < 3; kw++) {
            int iw = ow * 2 - 1 + kw;
            if (iw < 0 || iw >= 256) continue;
            float4 xv = *(const float4*)(x + (size_t)(ih * 256 + iw) * 192 + c);
            float4 wv = *(const float4*)(w + (kh * 3 + kw) * 192 + c);
            s.x += xv.x * wv.x; s.y += xv.y * wv.y;
            s.z += xv.z * wv.z; s.w += xv.w * wv.w;
        }
    }
    *(float4*)(adw + (size_t)p * 192 + c) = s;
}

// ---------------------------------------------------------------------------
// Neighborhood attention v8: MFMA, phase-split (see header comment).
// grid 6144 (XCD-chunked), block 256 = 4 waves.
// ---------------------------------------------------------------------------
__global__ __launch_bounds__(256) void na_attn_k(
    const bf16_t* __restrict__ nap, const bf16_t* __restrict__ vt,
    const float* __restrict__ rpb, bf16_t* __restrict__ outp)
{
    __shared__ float rpb_s[176];
    // [wave][q][7 rows x 20 words]: row stride 20 (16B-aligned reads),
    // q stride 140 -> writes/reads <=2-way bank aliased (free).
    __shared__ __align__(16) unsigned P_s[4][16][140];

    const int bid  = blockIdx.x;
    const int work = (bid & 7) * 768 + (bid >> 3);
    const int z    = work >> 8;          // 0..23 : h*4+par
    const int rem  = work & 255;
    const int pi   = rem >> 1;
    const int xh   = rem & 1;

    const int t = threadIdx.x;
    const int wv = t >> 6, lane = t & 63;
    const int lm = lane & 15, lq = lane >> 4;
    const int h = z >> 2, par = z & 3;

    if (t < 169) rpb_s[t] = rpb[h * 169 + t];
    __syncthreads();

    const int pj0 = xh * 64 + wv * 16;
    const int si  = min(max(pi - 3, 0), 121);
    const int rbh0 = si - pi + 6;
    const int c0  = min(max(pj0 - 3, 0), 121) & ~7;

    const size_t plane = (size_t)65536 * 32;
    const size_t poff  = (size_t)(par * 16384) * 32;
    const bf16_t* qpl = nap + (size_t)h * plane + poff;
    const bf16_t* kpl = nap + (size_t)(6 + h) * plane + poff;
    const bf16_t* vtpl = vt + ((size_t)z << 19);        // [d][pix]

    const short8 qf = *(const short8*)(qpl + ((size_t)(pi * 128 + pj0 + lm)) * 32 + lq * 8);

    int offc[4][2]; bool vm[4][2];
#pragma unroll
    for (int r = 0; r < 4; r++) {
        int q = lq * 4 + r, pj = pj0 + q;
        int sj = min(max(pj - 3, 0), 121);
#pragma unroll
        for (int t2 = 0; t2 < 2; t2++) {
            int c = c0 + 2 * lm + t2;
            vm[r][t2] = (c >= sj) && (c <= sj + 6);
            offc[r][t2] = min(max(c - pj + 6, 0), 12);
        }
    }
    const int kc0 = min(c0 + 2 * lm,     127) * 64;   // byte offsets (64B/px)
    const int kc1 = min(c0 + 2 * lm + 1, 127) * 64;
    const int vcol = c0 + (lq << 3);
    const size_t vb0 = (size_t)lm * 16384;            // d = lm
    const size_t vb1 = (size_t)(lm + 16) * 16384;     // d = 16+lm

    const float scale = 0.17677669529663687f; // 32^-0.5
    const f32x4 zz = {};

    // ---- phase 1: all QK^T MFMAs (independent; loads stream) ----
    f32x4 s[7][2];
#pragma unroll
    for (int rr = 0; rr < 7; rr++) {
        const char* krow = (const char*)kpl + (size_t)((si + rr) * 128) * 64;
        short8 kf0 = *(const short8*)(krow + kc0 + lq * 16);
        short8 kf1 = *(const short8*)(krow + kc1 + lq * 16);
        s[rr][0] = __builtin_amdgcn_mfma_f32_16x16x32_bf16(qf, kf0, zz, 0, 0, 0);
        s[rr][1] = __builtin_amdgcn_mfma_f32_16x16x32_bf16(qf, kf1, zz, 0, 0, 0);
    }

    // ---- phase 2: all exps + P pack -> LDS ----
    float sums[4] = {0.f, 0.f, 0.f, 0.f};
#pragma unroll
    for (int rr = 0; rr < 7; rr++) {
        const float* br = rpb_s + (rbh0 + rr) * 13;
#pragma unroll
        for (int r = 0; r < 4; r++) {
            float a0 = __expf(fmaf(s[rr][0][r], scale, br[offc[r][0]]));
            float a1 = __expf(fmaf(s[rr][1][r], scale, br[offc[r][1]]));
            a0 = vm[r][0] ? a0 : 0.f;
            a1 = vm[r][1] ? a1 : 0.f;
            sums[r] += a0 + a1;
            unsigned pr;
            asm("v_cvt_pk_bf16_f32 %0, %1, %2" : "=v"(pr) : "v"(a0), "v"(a1));
            P_s[wv][lq * 4 + r][rr * 20 + lm] = pr;   // slots 2lm, 2lm+1
        }
    }

    // ---- phase 3: PV (2 accumulator pairs halve the serial chain) ----
    f32x4 o0a = {}, o0b = {}, o1a = {}, o1b = {};
#pragma unroll
    for (int rr = 0; rr < 7; rr++) {
        const short8 pf = *(const short8*)&P_s[wv][lm][rr * 20 + lq * 4];
        int rowo = min((si + rr) * 128 + vcol, 16376);
        short8 vf0 = *(const short8*)(vtpl + vb0 + rowo);
        short8 vf1 = *(const short8*)(vtpl + vb1 + rowo);
        if (rr & 1) {
            o0b = __builtin_amdgcn_mfma_f32_16x16x32_bf16(pf, vf0, o0b, 0, 0, 0);
            o1b = __builtin_amdgcn_mfma_f32_16x16x32_bf16(pf, vf1, o1b, 0, 0, 0);
        } else {
            o0a = __builtin_amdgcn_mfma_f32_16x16x32_bf16(pf, vf0, o0a, 0, 0, 0);
            o1a = __builtin_amdgcn_mfma_f32_16x16x32_bf16(pf, vf1, o1a, 0, 0, 0);
        }
    }
    f32x4 o0 = o0a + o0b, o1 = o1a + o1b;

#pragma unroll
    for (int r = 0; r < 4; r++) {
        float sm = sums[r];
        sm += __shfl_xor(sm, 1, 64);
        sm += __shfl_xor(sm, 2, 64);
        sm += __shfl_xor(sm, 4, 64);
        sm += __shfl_xor(sm, 8, 64);
        sums[r] = 1.0f / sm;
    }

    const int gi = par >> 1, gj = par & 1;
    const int i0 = pi * 2 + gi;
    bf16_t* ob = outp + ((size_t)i0 * 256 + gj) * 192 + h * 32 + lm;
#pragma unroll
    for (int r = 0; r < 4; r++) {
        int q = lq * 4 + r;
        size_t px = (size_t)(pj0 + q) * 2 * 192;
        ob[px]      = f2bf(o0[r] * sums[r]);
        ob[px + 16] = f2bf(o1[r] * sums[r]);
    }
}

// ---------------------------------------------------------------------------
// Stripe stage 1 v3 (MFMA): one wave = one (window, head). (verified R10)
// ---------------------------------------------------------------------------
__global__ __launch_bounds__(256) void attn1_k(
    const float* __restrict__ apw,    // (16384,96) fp32
    const bf16_t* __restrict__ qkvs,  // (65536,288) bf16
    const float* __restrict__ b1pT,   // (6,1024): [h][m*16+n2]
    const float* __restrict__ ls1,
    float* __restrict__ x1)           // (1024,6,16,16) fp32
{
    __shared__ float bT_s[1024];
    __shared__ __align__(16) unsigned P_s[4][16][36];

    const int t = threadIdx.x;
    const int wv = t >> 6, lane = t & 63;
    const int lm = lane & 15, lq = lane >> 4;
    const int h = blockIdx.y;
    const int w = blockIdx.x * 4 + wv;
    const int wi = w >> 5, wj = w & 31;

#pragma unroll
    for (int i = 0; i < 4; i++) bT_s[i * 256 + t] = b1pT[h * 1024 + i * 256 + t];
    __syncthreads();

    const float scale = __expf(fminf(ls1[h], 4.605170185988091f));

    // ---- anchors -> B-frag (col=anchor=lm, k=d=lq*8+i; d<16 so lq<2) ----
    short8 af = {};
    float an2 = 0.f;
    {
        int ay = wi * 4 + (lm >> 2), ax = wj * 4 + (lm & 3);
        const float* ap = apw + (size_t)(ay * 128 + ax) * 96 + h * 16;
        if (lq < 2) {
            float4 v0 = *(const float4*)(ap + lq * 8);
            float4 v1 = *(const float4*)(ap + lq * 8 + 4);
            float vs[8] = {v0.x, v0.y, v0.z, v0.w, v1.x, v1.y, v1.z, v1.w};
            unsigned* au = (unsigned*)&af;
#pragma unroll
            for (int j2 = 0; j2 < 4; j2++) {
                unsigned u = pk2(vs[2 * j2], vs[2 * j2 + 1]);
                au[j2] = u;
                float lo = __uint_as_float(u << 16);
                float hi = __uint_as_float(u & 0xffff0000u);
                an2 += lo * lo + hi * hi;   // norm of the ROUNDED anchor
            }
        }
    }
    an2 += __shfl_xor(an2, 16, 64);
    an2 += __shfl_xor(an2, 32, 64);
    const float sa = scale / fmaxf(sqrtf(an2), 1e-12f);  // fold anchor norm

    const f32x4 zz = {};
    f32x4 o = {};
    float sum = 0.f;

#pragma unroll
    for (int g = 0; g < 2; g++) {
#pragma unroll
        for (int tt = 0; tt < 2; tt++) {
            const int tile = g * 2 + tt;
            int py = wi * 8 + tile * 2 + (lm >> 3);
            int px = wj * 8 + (lm & 7);
            const bf16_t* kp = qkvs + (size_t)(py * 256 + px) * 288 + 96 + h * 16;
            short8 kf = {};
            float kn2 = 0.f;
            float klo[4], khi[4];
            if (lq < 2) {
                uint4 kr = *(const uint4*)(kp + lq * 8);
                unsigned ku[4] = {kr.x, kr.y, kr.z, kr.w};
#pragma unroll
                for (int j2 = 0; j2 < 4; j2++) {
                    klo[j2] = __uint_as_float(ku[j2] << 16);
                    khi[j2] = __uint_as_float(ku[j2] & 0xffff0000u);
                    kn2 += klo[j2] * klo[j2] + khi[j2] * khi[j2];
                }
            }
            kn2 += __shfl_xor(kn2, 16, 64);
            kn2 += __shfl_xor(kn2, 32, 64);
            float rk = 1.0f / fmaxf(sqrtf(kn2), 1e-12f);
            if (lq < 2) {
                unsigned* kuo = (unsigned*)&kf;
#pragma unroll
                for (int j2 = 0; j2 < 4; j2++)
                    kuo[j2] = pk2(klo[j2] * rk, khi[j2] * rk);
            }
            f32x4 s = __builtin_amdgcn_mfma_f32_16x16x32_bf16(kf, af, zz, 0, 0, 0);
            float e[4];
#pragma unroll
            for (int r = 0; r < 4; r++) {
                e[r] = __expf(fmaf(s[r], sa,
                              bT_s[((tile * 16 + lq * 4 + r) << 4) + lm]));
                sum += e[r];
            }
            P_s[wv][lm][tile * 8 + lq * 2]     = pk2(e[0], e[1]);
            P_s[wv][lm][tile * 8 + lq * 2 + 1] = pk2(e[2], e[3]);
        }
        // ---- PV for keys g*32 .. g*32+31 ----
        const short8 pf = *(const short8*)&P_s[wv][lm][g * 16 + lq * 4];
        short8 vf;
        int pyv = wi * 8 + g * 4 + lq;
        const bf16_t* vrow = qkvs + (size_t)(pyv * 256 + wj * 8) * 288 + 192 + h * 16 + lm;
#pragma unroll
        for (int i = 0; i < 8; i++)
            ((bf16_t*)&vf)[i] = vrow[(size_t)i * 288];
        o = __builtin_amdgcn_mfma_f32_16x16x32_bf16(pf, vf, o, 0, 0, 0);
    }

    sum += __shfl_xor(sum, 16, 64);
    sum += __shfl_xor(sum, 32, 64);
    const float inv = 1.0f / sum;
    float* xp = x1 + ((size_t)w * 6 + h) * 256;
#pragma unroll
    for (int r = 0; r < 4; r++) {
        float iv = __shfl(inv, lq * 4 + r, 64);   // inv for anchor lq*4+r
        xp[(lq * 4 + r) * 16 + lm] = o[r] * iv;
    }
}

// Stripe stage 2 -> cat[:, 96:192] (bf16), window-reversed
__global__ __launch_bounds__(256) void attn2_k(
    const float* __restrict__ apw,
    const bf16_t* __restrict__ qkvs,
    const float* __restrict__ b2p,    // (6,1024): [h][n1*16+m]
    const float* __restrict__ ls2,
    const float* __restrict__ x1,
    bf16_t* __restrict__ cat)         // (65536,192) bf16, cols 96..191
{
    int tid = blockIdx.x * 256 + threadIdx.x;
    if (tid >= 1024 * 6 * 64) return;
    int n1 = tid & 63;
    int h = (tid >> 6) % 6;
    int w = tid / 384;
    int wi = w >> 5, wj = w & 31;
    float scale = __expf(fminf(ls2[h], 4.605170185988091f));

    int qy = wi * 8 + (n1 >> 3), qx = wj * 8 + (n1 & 7);
    const bf16_t* qp = qkvs + (size_t)(qy * 256 + qx) * 288 + h * 16;
    float qv[16];
    ld_bf8(qp, qv); ld_bf8(qp + 8, qv + 8);
    float nrm = 0.f;
#pragma unroll
    for (int d = 0; d < 16; d++) nrm += qv[d] * qv[d];
    float innorm = 1.0f / fmaxf(sqrtf(nrm), 1e-12f);
#pragma unroll
    for (int d = 0; d < 16; d++) qv[d] *= innorm;

    const float* bp = b2p + h * 1024 + n1 * 16;
    float sum = 0.f;
    float acc[16] = {};
#pragma unroll
    for (int m = 0; m < 16; m++) {
        int ay = wi * 4 + (m >> 2), ax = wj * 4 + (m & 3);
        const float* ap = apw + (size_t)(ay * 128 + ax) * 96 + h * 16;
        float dot = 0.f, kn = 0.f;
#pragma unroll
        for (int d = 0; d < 16; d += 4) {
            float4 v = *(const float4*)(ap + d);
            dot += qv[d] * v.x + qv[d + 1] * v.y + qv[d + 2] * v.z + qv[d + 3] * v.w;
            kn += v.x * v.x + v.y * v.y + v.z * v.z + v.w * v.w;
        }
        dot *= 1.0f / fmaxf(sqrtf(kn), 1e-12f);
        float e = __expf(fmaf(dot, scale, bp[m]));
        sum += e;
        const float* vp = x1 + ((size_t)w * 6 + h) * 256 + m * 16;
#pragma unroll
        for (int d = 0; d < 16; d += 4) {
            float4 v = *(const float4*)(vp + d);
            acc[d] += e * v.x; acc[d + 1] += e * v.y;
            acc[d + 2] += e * v.z; acc[d + 3] += e * v.w;
        }
    }
    float inv = 1.0f / sum;
#pragma unroll
    for (int d = 0; d < 16; d++) acc[d] *= inv;
    bf16_t* op = cat + (size_t)(qy * 256 + qx) * 192 + 96 + h * 16;
    uint4 o0, o1;
    o0.x = pk2(acc[0], acc[1]);   o0.y = pk2(acc[2], acc[3]);
    o0.z = pk2(acc[4], acc[5]);   o0.w = pk2(acc[6], acc[7]);
    o1.x = pk2(acc[8], acc[9]);   o1.y = pk2(acc[10], acc[11]);
    o1.z = pk2(acc[12], acc[13]); o1.w = pk2(acc[14], acc[15]);
    *(uint4*)(op) = o0;
    *(uint4*)(op + 8) = o1;
}

extern "C" void kernel_launch(void* const* d_in, const int* in_sizes, int n_in,
                              void* d_out, int out_size, void* d_ws, size_t ws_size,
                              hipStream_t stream) {
    const float* x          = (const float*)d_in[0];
    const float* table      = (const float*)d_in[3];
    const int*   idx_a2w    = (const int*)d_in[4];
    const int*   idx_w2a    = (const int*)d_in[5];
    const float* qkv_w      = (const float*)d_in[6];
    const float* qkv_b      = (const float*)d_in[7];
    const float* adw_w      = (const float*)d_in[8];
    const float* adw_b      = (const float*)d_in[9];
    const float* apw_w      = (const float*)d_in[10];
    const float* apw_b      = (const float*)d_in[11];
    const float* na_qkv_w   = (const float*)d_in[12];
    const float* na_qkv_b   = (const float*)d_in[13];
    const float* na_after_w = (const float*)d_in[14];
    const float* na_after_b = (const float*)d_in[15];
    const float* na_rpb     = (const float*)d_in[16];
    const float* ls1        = (const float*)d_in[17];
    const float* cpb1_w1    = (const float*)d_in[18];
    const float* cpb1_b1    = (const float*)d_in[19];
    const float* cpb1_w2    = (const float*)d_in[20];
    const float* ls2        = (const float*)d_in[21];
    const float* cpb2_w1    = (const float*)d_in[22];
    const float* cpb2_b1    = (const float*)d_in[23];
    const float* cpb2_w2    = (const float*)d_in[24];
    const float* proj_w     = (const float*)d_in[25];
    const float* proj_b     = (const float*)d_in[26];
    float* out = (float*)d_out;
    (void)in_sizes; (void)n_in; (void)out_size; (void)ws_size;

    // ---- byte-based workspace allocator (256B aligned) ----
    char* base = (char*)d_ws;
    size_t off = 0;
    auto alloc = [&](size_t bytes) {
        off = (off + 255) & ~(size_t)255;
        void* p = base + off; off += bytes; return p;
    };
    float*  bna    = (float*)alloc(576 * 4);
    float*  bt1    = (float*)alloc(225 * 6 * 4);
    float*  bt2    = (float*)alloc(225 * 6 * 4);
    float*  b1pT   = (float*)alloc(6144 * 4);
    float*  b2p    = (float*)alloc(6144 * 4);
    float*  qkv_wT = (float*)alloc(288 * 192 * 4);
    bf16_t* Wna_t  = (bf16_t*)alloc(576 * 192 * 2);
    bf16_t* Ws_t   = (bf16_t*)alloc(288 * 192 * 2);
    bf16_t* Waft_t = (bf16_t*)alloc(96 * 192 * 2);
    bf16_t* Wproj_t= (bf16_t*)alloc(192 * 192 * 2);
    bf16_t* qkvs   = (bf16_t*)alloc((size_t)65536 * 288 * 2);  // 37.75 MB
    char*   naR    = (char*)alloc((size_t)65536 * 576 * 2);    // 75.5 MB region
    char*   R      = (char*)alloc((size_t)65536 * 192 * 2);    // 25.2 MB region
    float*  apw    = (float*)alloc((size_t)16384 * 96 * 4);    // 6.3 MB
    // region aliases (strictly sequential lifetimes on the in-order stream):
    bf16_t* naqkv   = (bf16_t*)naR;               // naqkv gemm .. na_attn (planes)
    float*  x1      = (float*)naR;                // attn1 .. attn2 (6.3 MB)
    bf16_t* cat     = (bf16_t*)(naR + (8 << 20)); // na_after .. proj (25.2 MB)
    bf16_t* xb      = (bf16_t*)R;                 // cvt .. naqkv gemm (25.2 MB)
    float*  adw     = (float*)R;                  // dwconv .. apw gemm (12.6 MB)
    bf16_t* xna_pre = (bf16_t*)R;                 // na_attn .. na_after (25.2 MB)
    // VT planes (24 MiB) live in d_out-as-scratch: out is only written by the
    // final proj gemm, which fully overwrites it.
    bf16_t* vt      = (bf16_t*)out;               // vtpose .. na_attn

    // Tiny precomputes (independent)
    tpose_qkvw_k<<<216, 256, 0, stream>>>(qkv_w, qkv_wT);
    fold_wna_t_k<<<432, 256, 0, stream>>>(qkv_wT, na_qkv_w, Wna_t);
    fold_bna_k<<<3, 256, 0, stream>>>(qkv_b, na_qkv_w, na_qkv_b, bna);
    cpb_k<<<6, 256, 0, stream>>>(table, cpb1_w1, cpb1_b1, cpb1_w2, bt1);
    cpb_k<<<6, 256, 0, stream>>>(table, cpb2_w1, cpb2_b1, cpb2_w2, bt2);
    sigb1T_k<<<24, 256, 0, stream>>>(bt1, idx_a2w, b1pT);
    sigb_k<<<24, 256, 0, stream>>>(bt2, idx_w2a, b2p);
    tcvt_k<<<216, 256, 0, stream>>>(qkv_w, Ws_t, 192, 288, 576, 288);
    tcvt_k<<<72, 256, 0, stream>>>(na_after_w, Waft_t, 192, 96, 96, 0);
    tcvt_k<<<144, 256, 0, stream>>>(proj_w, Wproj_t, 192, 192, 192, 0);
    cvt_bf16_k<<<6144, 256, 0, stream>>>(x, xb, 65536 * 192 / 8);

    // Stripe qkv: xb @ Ws_t^T + b -> qkvs bf16 (65536,288), row-major
    mfma_gemm_k<192, 0, 3, bf16_t><<<1536, 256, 0, stream>>>(
        xb, Ws_t, qkv_b + 288, qkvs, 192, 192, 288);

    // Folded NA qkv: xb @ Wna_t^T + bna -> naqkv (Q/K/V planes, coalesced)
    mfma_gemm_k<192, 1, 6, bf16_t><<<3072, 256, 0, stream>>>(
        xb, Wna_t, bna, naqkv, 192, 192, 576);

    // V planes -> VT planes (scratch in d_out)
    vtpose_k<<<3072, 256, 0, stream>>>(naqkv, vt);

    // Anchor: depthwise conv (xb dead -> adw in R), pointwise GEMM -> apw
    dwconv_k<<<3072, 256, 0, stream>>>(x, adw_w, adw_b, adw);
    gemm_k<float, float><<<dim3(2, 256), 256, 0, stream>>>(
        adw, apw_w, apw_b, apw, 16384, 96, 192, 192, 96, 96);

    // Neighborhood attention (adw dead -> xna_pre in R)
    na_attn_k<<<6144, 256, 0, stream>>>(naqkv, vt, na_rpb, xna_pre);

    // na_after: xna_pre @ Waft_t^T + b -> cat[:,0:96]  (naqkv dead)
    mfma_gemm_k<192, 0, 1, bf16_t><<<512, 256, 0, stream>>>(
        xna_pre, Waft_t, na_after_b, cat, 192, 192, 192);

    // Stripe attention -> x1, then cat[:,96:192]
    attn1_k<<<dim3(256, 6), 256, 0, stream>>>(apw, qkvs, b1pT, ls1, x1);
    attn2_k<<<1536, 256, 0, stream>>>(apw, qkvs, b2p, ls2, x1, cat);

    // Final projection: cat @ Wproj_t^T + proj_b -> out fp32 (vt dead)
    mfma_gemm_k<192, 0, 2, float><<<1024, 256, 0, stream>>>(
        cat, Wproj_t, proj_b, out, 192, 192, 192);
}

// Round 7
// 618.975 us; speedup vs baseline: 1.0042x; 1.0042x over previous
//
#include <hip/hip_runtime.h>
#include <math.h>

// ---------------------------------------------------------------------------
// MixedAttention: H=W=256, C=192, HEADS=6, NA: K=7 DIL=2 hd=32,
// stripe: WS=8 AWS=4 hs=16, 1024 windows.
// R14: revert R13 phase-split (LDS 36KB killed occupancy, no pipelining
// gain: 88->91us). Back to the R12 na_attn body (6KB LDS) + two latency
// fixes: (1) all 14 VT loads hoisted to registers before the row loop
// (loop-independent addresses; V no longer sits at the end of the per-row
// serial chain); (2) vtpose gets the SAME plane->XCD mapping as na_attn and
// runs immediately before it, so each XCD's 3 VT planes (3MB) are L2-hot.
// R12 model: FETCH 36.9MB == first-touch footprint, wave span ~27k cycles
// -> chain latency-bound, not BW/VALU.
// ---------------------------------------------------------------------------

typedef unsigned short bf16_t;
typedef __attribute__((ext_vector_type(8))) short short8;   // MFMA A/B frag (8 bf16)
typedef __attribute__((ext_vector_type(4))) float f32x4;    // MFMA C/D frag

__device__ inline float bf2f(bf16_t v) { return __uint_as_float((unsigned)v << 16); }
__device__ inline bf16_t f2bf(float f) {
    unsigned u = __float_as_uint(f);
    unsigned r = (u + 0x7fffu + ((u >> 16) & 1u)) >> 16;   // RNE, finite inputs
    return (bf16_t)r;
}
__device__ inline float cvt(float v) { return v; }
__device__ inline float cvt(bf16_t v) { return bf2f(v); }
__device__ inline void sto(float* p, float v) { *p = v; }
__device__ inline void sto(bf16_t* p, float v) { *p = f2bf(v); }

// load 8 consecutive bf16 (16B aligned) -> 8 floats
__device__ inline void ld_bf8(const bf16_t* p, float* d) {
    uint4 r = *(const uint4*)p;
    d[0] = __uint_as_float(r.x << 16); d[1] = __uint_as_float(r.x & 0xffff0000u);
    d[2] = __uint_as_float(r.y << 16); d[3] = __uint_as_float(r.y & 0xffff0000u);
    d[4] = __uint_as_float(r.z << 16); d[5] = __uint_as_float(r.z & 0xffff0000u);
    d[6] = __uint_as_float(r.w << 16); d[7] = __uint_as_float(r.w & 0xffff0000u);
}
__device__ inline unsigned pk2(float a, float b) {
    return (unsigned)f2bf(a) | ((unsigned)f2bf(b) << 16);
}

// ---------------------------------------------------------------------------
// MFMA GEMM: C[M,N] = A[M,K]bf16 @ Bt[N,K]^T + bias. Tile 128x96, 4 waves,
// each wave 64x48 = 4x3 16x16 frags, K=192 fully unrolled, no LDS.
// 1D grid (multiple of 8) with bijective XCD chunk swizzle; NCOL = column
// tiles per row so each XCD owns contiguous rows x all cols (A L2 reuse).
// NA=1: scatter-store into parity-split head planes:
//   ((which*6+h)*65536 + par*16384 + pixin)*32 + d   (Q,K,V all plane-major)
// ---------------------------------------------------------------------------
template <int KD, int NA, int NCOL, typename TO>
__global__ __launch_bounds__(256) void mfma_gemm_k(
    const bf16_t* __restrict__ A, const bf16_t* __restrict__ Bt,
    const float* __restrict__ bias, TO* __restrict__ C,
    int lda, int ldb, int ldc)
{
    const int bid  = blockIdx.x;
    const int work = (bid & 7) * (gridDim.x >> 3) + (bid >> 3);
    const int brow = work / NCOL;
    const int bcol = work - brow * NCOL;

    const int t = threadIdx.x;
    const int lane = t & 63, wave = t >> 6;
    const int wr = wave >> 1, wc = wave & 1;
    const int m0 = brow * 128 + wr * 64;
    const int n0 = bcol * 96 + wc * 48;
    const int lm = lane & 15;
    const int q  = lane >> 4;

    f32x4 acc[4][3] = {};
    const bf16_t* ap = A + (size_t)(m0 + lm) * lda + q * 8;
    const bf16_t* bp = Bt + (size_t)(n0 + lm) * ldb + q * 8;

#pragma unroll
    for (int k0 = 0; k0 < KD; k0 += 32) {
        short8 af[4], bf[3];
#pragma unroll
        for (int mi = 0; mi < 4; mi++)
            af[mi] = *(const short8*)(ap + (size_t)(mi * 16) * lda + k0);
#pragma unroll
        for (int ni = 0; ni < 3; ni++)
            bf[ni] = *(const short8*)(bp + (size_t)(ni * 16) * ldb + k0);
#pragma unroll
        for (int mi = 0; mi < 4; mi++)
#pragma unroll
            for (int ni = 0; ni < 3; ni++)
                acc[mi][ni] = __builtin_amdgcn_mfma_f32_16x16x32_bf16(
                    af[mi], bf[ni], acc[mi][ni], 0, 0, 0);
    }

#pragma unroll
    for (int mi = 0; mi < 4; mi++) {
#pragma unroll
        for (int ni = 0; ni < 3; ni++) {
            int col = n0 + ni * 16 + lm;
            float bv = bias[col];
            if (NA) {
                int which = col / 192;
                int hh = (col % 192) / 32;
                int d  = col % 32;
                size_t pbase = ((size_t)which * 6 + hh) * 2097152 + d;
#pragma unroll
                for (int r = 0; r < 4; r++) {
                    int row = m0 + mi * 16 + q * 4 + r;
                    int ii = row >> 8, jj = row & 255;
                    int par = ((ii & 1) << 1) | (jj & 1);
                    int pixin = (ii >> 1) * 128 + (jj >> 1);
                    sto(&C[pbase + ((size_t)(par * 16384 + pixin) << 5)],
                        acc[mi][ni][r] + bv);
                }
            } else {
#pragma unroll
                for (int r = 0; r < 4; r++) {
                    int row = m0 + mi * 16 + q * 4 + r;
                    sto(&C[(size_t)row * ldc + col], acc[mi][ni][r] + bv);
                }
            }
        }
    }
}

// V planes ([pix][d]) -> VT planes ([d][pix]) via LDS tile transpose.
// grid 3072, XCD-chunked with the SAME plane->XCD mapping as na_attn:
// XCD k transposes planes z = 3k..3k+2 (384 works = 3 planes x 128 tiles),
// so the VT data na_attn reads is in the right XCD's L2.
__global__ __launch_bounds__(256) void vtpose_k(
    const bf16_t* __restrict__ nap, bf16_t* __restrict__ vt)
{
    __shared__ unsigned short tl[32][144];   // [d][px], pad 16 px
    const int bid = blockIdx.x;
    const int work = (bid & 7) * 384 + (bid >> 3);
    const int z = work >> 7;         // h*4+par (3 planes per XCD)
    const int tile = work & 127;
    const int h = z >> 2, par = z & 3;
    const int pix0 = tile << 7;

    const bf16_t* sp = nap + (size_t)(12 + h) * 2097152
                     + ((size_t)(par * 16384 + pix0) << 5);
    const int t = threadIdx.x;
    {
        const int px = t & 127, half = t >> 7;        // half: d 0..15 / 16..31
        uint4 r0 = *(const uint4*)(sp + px * 32 + half * 16);
        uint4 r1 = *(const uint4*)(sp + px * 32 + half * 16 + 8);
        const unsigned short* u0 = (const unsigned short*)&r0;
        const unsigned short* u1 = (const unsigned short*)&r1;
#pragma unroll
        for (int i = 0; i < 8; i++) tl[half * 16 + i][px] = u0[i];
#pragma unroll
        for (int i = 0; i < 8; i++) tl[half * 16 + 8 + i][px] = u1[i];
    }
    __syncthreads();
    {
        const int d = t >> 3, g = t & 7;              // 32 d x 8 groups of 16 px
        unsigned short buf[16];
#pragma unroll
        for (int i = 0; i < 16; i++) buf[i] = tl[d][g * 16 + i];
        bf16_t* dp = vt + ((size_t)z << 19) + ((size_t)d << 14) + pix0 + g * 16;
        *(uint4*)dp = *(uint4*)buf;
        *(uint4*)(dp + 8) = *(uint4*)(buf + 8);
    }
}

// x fp32 -> bf16, 8 elems/thread
__global__ __launch_bounds__(256) void cvt_bf16_k(
    const float* __restrict__ src, bf16_t* __restrict__ dst, int n8)
{
    int tid = blockIdx.x * 256 + threadIdx.x;
    if (tid >= n8) return;
    float4 a = ((const float4*)src)[tid * 2];
    float4 b = ((const float4*)src)[tid * 2 + 1];
    uint4 o;
    o.x = pk2(a.x, a.y); o.y = pk2(a.z, a.w);
    o.z = pk2(b.x, b.y); o.w = pk2(b.z, b.w);
    ((uint4*)dst)[tid] = o;
}

// Wt[n*Kd + k] = (bf16) W[k*ld + coloff + n]   (transpose + convert)
__global__ __launch_bounds__(256) void tcvt_k(
    const float* __restrict__ W, bf16_t* __restrict__ Wt,
    int Kd, int N, int ld, int coloff)
{
    int tid = blockIdx.x * 256 + threadIdx.x;
    if (tid >= Kd * N) return;
    int k = tid % Kd, n = tid / Kd;
    Wt[tid] = f2bf(W[(size_t)k * ld + coloff + n]);
}

// qkv_wT[j*192 + k] = qkv_w[k*576 + j], j < 288
__global__ __launch_bounds__(256) void tpose_qkvw_k(
    const float* __restrict__ W, float* __restrict__ WT)
{
    int tid = blockIdx.x * 256 + threadIdx.x;
    if (tid >= 288 * 192) return;
    int k = tid % 192, j = tid / 192;
    WT[tid] = W[(size_t)k * 576 + j];
}

// Wna_t[n*192 + k] = (bf16) sum_j qkv_wT[j,k] * na_qkv_w[j,n], j<288
__global__ __launch_bounds__(256) void fold_wna_t_k(
    const float* __restrict__ qkv_wT, const float* __restrict__ na_qkv_w,
    bf16_t* __restrict__ Wna_t)
{
    int tid = blockIdx.x * 256 + threadIdx.x;
    if (tid >= 576 * 192) return;
    int k = tid % 192, n = tid / 192;
    float acc = 0.f;
    for (int j = 0; j < 288; j++)
        acc += qkv_wT[j * 192 + k] * na_qkv_w[j * 576 + n];
    Wna_t[tid] = f2bf(acc);
}

__global__ __launch_bounds__(256) void fold_bna_k(
    const float* __restrict__ qkv_b, const float* __restrict__ na_qkv_w,
    const float* __restrict__ na_qkv_b, float* __restrict__ bna)
{
    int j = blockIdx.x * 256 + threadIdx.x;
    if (j >= 576) return;
    float acc = na_qkv_b[j];
    for (int k = 0; k < 288; k++)
        acc += qkv_b[k] * na_qkv_w[k * 576 + j];
    bna[j] = acc;
}

// bt[t,h] = (relu(table(225,2) @ w1 + b1) @ w2)[t,h]
__global__ __launch_bounds__(256) void cpb_k(
    const float* __restrict__ table, const float* __restrict__ w1,
    const float* __restrict__ b1, const float* __restrict__ w2,
    float* __restrict__ bt)
{
    int tid = blockIdx.x * 256 + threadIdx.x;
    if (tid >= 225 * 6) return;
    int h = tid % 6, t = tid / 6;
    float t0 = table[t * 2], t1 = table[t * 2 + 1];
    float acc = 0.f;
    for (int m = 0; m < 512; m++) {
        float hv = t0 * w1[m] + t1 * w1[512 + m] + b1[m];
        hv = fmaxf(hv, 0.f);
        acc += hv * w2[m * 6 + h];
    }
    bt[tid] = acc;
}

// b2p[h*1024 + n1*16 + m] = 16*sigmoid(bt[idx[n1*16+m]*6 + h])  (attn2)
__global__ __launch_bounds__(256) void sigb_k(
    const float* __restrict__ bt, const int* __restrict__ idx,
    float* __restrict__ bp)
{
    int tid = blockIdx.x * 256 + threadIdx.x;
    if (tid >= 6144) return;
    int h = tid >> 10, p = tid & 1023;
    bp[tid] = 16.0f / (1.0f + __expf(-bt[idx[p] * 6 + h]));
}

// b1pT[h*1024 + m*16 + n2] = 16*sigmoid(bt[idx[n2*64+m]*6 + h])  (attn1)
__global__ __launch_bounds__(256) void sigb1T_k(
    const float* __restrict__ bt, const int* __restrict__ idx,
    float* __restrict__ bp)
{
    int tid = blockIdx.x * 256 + threadIdx.x;
    if (tid >= 6144) return;
    int h = tid >> 10, p = tid & 1023;
    int m = p >> 4, n2 = p & 15;
    bp[tid] = 16.0f / (1.0f + __expf(-bt[idx[n2 * 64 + m] * 6 + h]));
}

// legacy fp32 tiled GEMM (kept for the small anchor-pointwise GEMM)
#define BM 64
#define BN 64
#define BKK 16
template <typename TA, typename TO>
__global__ __launch_bounds__(256) void gemm_k(
    const TA* __restrict__ A, const float* __restrict__ B,
    const float* __restrict__ bias, TO* __restrict__ C,
    int M, int N, int Kd, int lda, int ldb, int ldc)
{
    __shared__ float As[BKK][BM + 1];
    __shared__ float Bs[BKK][BN + 1];
    const int t  = threadIdx.x;
    const int tx = t & 15, ty = t >> 4;
    const int m0 = blockIdx.y * BM, n0 = blockIdx.x * BN;
    float acc[4][4] = {};

    for (int k0 = 0; k0 < Kd; k0 += BKK) {
#pragma unroll
        for (int i = 0; i < 4; i++) {
            int m = (t >> 4) + i * 16;
            int k = t & 15;
            int gm = m0 + m, gk = k0 + k;
            As[k][m] = (gm < M && gk < Kd) ? cvt(A[(size_t)gm * lda + gk]) : 0.f;
        }
#pragma unroll
        for (int i = 0; i < 4; i++) {
            int k = (t >> 6) + i * 4;
            int n = t & 63;
            int gk = k0 + k, gn = n0 + n;
            Bs[k][n] = (gk < Kd && gn < N) ? B[(size_t)gk * ldb + gn] : 0.f;
        }
        __syncthreads();
#pragma unroll
        for (int k = 0; k < BKK; k++) {
            float a[4], b[4];
#pragma unroll
            for (int i = 0; i < 4; i++) a[i] = As[k][ty * 4 + i];
#pragma unroll
            for (int j = 0; j < 4; j++) b[j] = Bs[k][tx * 4 + j];
#pragma unroll
            for (int i = 0; i < 4; i++)
#pragma unroll
                for (int j = 0; j < 4; j++) acc[i][j] += a[i] * b[j];
        }
        __syncthreads();
    }
#pragma unroll
    for (int i = 0; i < 4; i++) {
        int gm = m0 + ty * 4 + i;
        if (gm >= M) continue;
#pragma unroll
        for (int j = 0; j < 4; j++) {
            int gn = n0 + tx * 4 + j;
            if (gn >= N) continue;
            sto(&C[(size_t)gm * ldc + gn], acc[i][j] + bias[gn]);
        }
    }
}

// Depthwise 3x3 stride-2 pad-1 on x (256,256,192) -> adw (128,128,192) fp32
__global__ __launch_bounds__(256) void dwconv_k(
    const float* __restrict__ x, const float* __restrict__ w,
    const float* __restrict__ b, float* __restrict__ adw)
{
    int tid = blockIdx.x * 256 + threadIdx.x;
    if (tid >= 16384 * 48) return;
    int c4 = tid % 48;
    int p = tid / 48;
    int ow = p & 127, oh = p >> 7;
    int c = c4 * 4;
    float4 s = *(const float4*)(b + c);
#pragma unroll
    for (int kh = 0; kh < 3; kh++) {
        int ih = oh * 2 - 1 + kh;
        if (ih < 0 || ih >= 256) continue;
#pragma unroll
        for (int kw = 0; kw < 3; kw++) {
            int iw = ow * 2 - 1 + kw;
            if (iw < 0 || iw >= 256) continue;
            float4 xv = *(const float4*)(x + (size_t)(ih * 256 + iw) * 192 + c);
            float4 wv = *(const float4*)(w + (kh * 3 + kw) * 192 + c);
            s.x += xv.x * wv.x; s.y += xv.y * wv.y;
            s.z += xv.z * wv.z; s.w += xv.w * wv.w;
        }
    }
    *(float4*)(adw + (size_t)p * 192 + c) = s;
}

// ---------------------------------------------------------------------------
// Neighborhood attention v9: R12 body (6KB LDS, verified) + V register
// prefetch (all 14 VT loads hoisted out of the serial per-row chain).
// grid 6144 (XCD-chunked), block 256 = 4 waves.
// ---------------------------------------------------------------------------
__global__ __launch_bounds__(256) void na_attn_k(
    const bf16_t* __restrict__ nap, const bf16_t* __restrict__ vt,
    const float* __restrict__ rpb, bf16_t* __restrict__ outp)
{
    __shared__ float rpb_s[176];
    __shared__ __align__(16) unsigned P_s[4][16][20];   // [wave][q][slot-pair]

    const int bid  = blockIdx.x;
    const int work = (bid & 7) * 768 + (bid >> 3);
    const int z    = work >> 8;          // 0..23 : h*4+par
    const int rem  = work & 255;
    const int pi   = rem >> 1;
    const int xh   = rem & 1;

    const int t = threadIdx.x;
    const int wv = t >> 6, lane = t & 63;
    const int lm = lane & 15, lq = lane >> 4;
    const int h = z >> 2, par = z & 3;

    if (t < 169) rpb_s[t] = rpb[h * 169 + t];
    __syncthreads();

    const int pj0 = xh * 64 + wv * 16;
    const int si  = min(max(pi - 3, 0), 121);
    const int rbh0 = si - pi + 6;
    const int c0  = min(max(pj0 - 3, 0), 121) & ~7;

    const size_t plane = (size_t)65536 * 32;
    const size_t poff  = (size_t)(par * 16384) * 32;
    const bf16_t* qpl = nap + (size_t)h * plane + poff;
    const bf16_t* kpl = nap + (size_t)(6 + h) * plane + poff;
    const bf16_t* vtpl = vt + ((size_t)z << 19);        // [d][pix]

    const short8 qf = *(const short8*)(qpl + ((size_t)(pi * 128 + pj0 + lm)) * 32 + lq * 8);

    int offc[4][2]; bool vm[4][2];
#pragma unroll
    for (int r = 0; r < 4; r++) {
        int q = lq * 4 + r, pj = pj0 + q;
        int sj = min(max(pj - 3, 0), 121);
#pragma unroll
        for (int t2 = 0; t2 < 2; t2++) {
            int c = c0 + 2 * lm + t2;
            vm[r][t2] = (c >= sj) && (c <= sj + 6);
            offc[r][t2] = min(max(c - pj + 6, 0), 12);
        }
    }
    const int kc0 = min(c0 + 2 * lm,     127) * 64;   // byte offsets (64B/px)
    const int kc1 = min(c0 + 2 * lm + 1, 127) * 64;
    const int vcol = c0 + (lq << 3);
    const size_t vb0 = (size_t)lm * 16384;            // d = lm
    const size_t vb1 = (size_t)(lm + 16) * 16384;     // d = 16+lm

    // ---- V register prefetch: loop-independent addresses, issue all 14 ----
    short8 vf[7][2];
#pragma unroll
    for (int rr = 0; rr < 7; rr++) {
        int rowo = min((si + rr) * 128 + vcol, 16376);
        vf[rr][0] = *(const short8*)(vtpl + vb0 + rowo);
        vf[rr][1] = *(const short8*)(vtpl + vb1 + rowo);
    }

    const float scale = 0.17677669529663687f; // 32^-0.5
    f32x4 o0 = {}, o1 = {};
    float sums[4] = {0.f, 0.f, 0.f, 0.f};
    const f32x4 zz = {};

#pragma unroll
    for (int rr = 0; rr < 7; rr++) {
        const char* krow = (const char*)kpl + (size_t)((si + rr) * 128) * 64;

        short8 kf0 = *(const short8*)(krow + kc0 + lq * 16);
        short8 kf1 = *(const short8*)(krow + kc1 + lq * 16);
        f32x4 s0 = __builtin_amdgcn_mfma_f32_16x16x32_bf16(qf, kf0, zz, 0, 0, 0);
        f32x4 s1 = __builtin_amdgcn_mfma_f32_16x16x32_bf16(qf, kf1, zz, 0, 0, 0);

        const float* br = rpb_s + (rbh0 + rr) * 13;
        float e0[4], e1[4];
#pragma unroll
        for (int r = 0; r < 4; r++) {
            float a0 = __expf(fmaf(s0[r], scale, br[offc[r][0]]));
            float a1 = __expf(fmaf(s1[r], scale, br[offc[r][1]]));
            a0 = vm[r][0] ? a0 : 0.f;
            a1 = vm[r][1] ? a1 : 0.f;
            e0[r] = a0; e1[r] = a1;
            sums[r] += a0 + a1;
        }
#pragma unroll
        for (int r = 0; r < 4; r++) {
            unsigned pr;
            asm("v_cvt_pk_bf16_f32 %0, %1, %2" : "=v"(pr) : "v"(e0[r]), "v"(e1[r]));
            P_s[wv][lq * 4 + r][lm] = pr;   // slots 2lm (lo), 2lm+1 (hi)
        }
        const short8 pf = *(const short8*)((const bf16_t*)P_s[wv][lm] + lq * 8);

        o0 = __builtin_amdgcn_mfma_f32_16x16x32_bf16(pf, vf[rr][0], o0, 0, 0, 0);
        o1 = __builtin_amdgcn_mfma_f32_16x16x32_bf16(pf, vf[rr][1], o1, 0, 0, 0);
    }

#pragma unroll
    for (int r = 0; r < 4; r++) {
        float s = sums[r];
        s += __shfl_xor(s, 1, 64);
        s += __shfl_xor(s, 2, 64);
        s += __shfl_xor(s, 4, 64);
        s += __shfl_xor(s, 8, 64);
        sums[r] = 1.0f / s;
    }

    const int gi = par >> 1, gj = par & 1;
    const int i0 = pi * 2 + gi;
    bf16_t* ob = outp + ((size_t)i0 * 256 + gj) * 192 + h * 32 + lm;
#pragma unroll
    for (int r = 0; r < 4; r++) {
        int q = lq * 4 + r;
        size_t px = (size_t)(pj0 + q) * 2 * 192;
        ob[px]      = f2bf(o0[r] * sums[r]);
        ob[px + 16] = f2bf(o1[r] * sums[r]);
    }
}

// ---------------------------------------------------------------------------
// Stripe stage 1 v3 (MFMA): one wave = one (window, head). (verified R10)
// ---------------------------------------------------------------------------
__global__ __launch_bounds__(256) void attn1_k(
    const float* __restrict__ apw,    // (16384,96) fp32
    const bf16_t* __restrict__ qkvs,  // (65536,288) bf16
    const float* __restrict__ b1pT,   // (6,1024): [h][m*16+n2]
    const float* __restrict__ ls1,
    float* __restrict__ x1)           // (1024,6,16,16) fp32
{
    __shared__ float bT_s[1024];
    __shared__ __align__(16) unsigned P_s[4][16][36];

    const int t = threadIdx.x;
    const int wv = t >> 6, lane = t & 63;
    const int lm = lane & 15, lq = lane >> 4;
    const int h = blockIdx.y;
    const int w = blockIdx.x * 4 + wv;
    const int wi = w >> 5, wj = w & 31;

#pragma unroll
    for (int i = 0; i < 4; i++) bT_s[i * 256 + t] = b1pT[h * 1024 + i * 256 + t];
    __syncthreads();

    const float scale = __expf(fminf(ls1[h], 4.605170185988091f));

    // ---- anchors -> B-frag (col=anchor=lm, k=d=lq*8+i; d<16 so lq<2) ----
    short8 af = {};
    float an2 = 0.f;
    {
        int ay = wi * 4 + (lm >> 2), ax = wj * 4 + (lm & 3);
        const float* ap = apw + (size_t)(ay * 128 + ax) * 96 + h * 16;
        if (lq < 2) {
            float4 v0 = *(const float4*)(ap + lq * 8);
            float4 v1 = *(const float4*)(ap + lq * 8 + 4);
            float vs[8] = {v0.x, v0.y, v0.z, v0.w, v1.x, v1.y, v1.z, v1.w};
            unsigned* au = (unsigned*)&af;
#pragma unroll
            for (int j2 = 0; j2 < 4; j2++) {
                unsigned u = pk2(vs[2 * j2], vs[2 * j2 + 1]);
                au[j2] = u;
                float lo = __uint_as_float(u << 16);
                float hi = __uint_as_float(u & 0xffff0000u);
                an2 += lo * lo + hi * hi;   // norm of the ROUNDED anchor
            }
        }
    }
    an2 += __shfl_xor(an2, 16, 64);
    an2 += __shfl_xor(an2, 32, 64);
    const float sa = scale / fmaxf(sqrtf(an2), 1e-12f);  // fold anchor norm

    const f32x4 zz = {};
    f32x4 o = {};
    float sum = 0.f;

#pragma unroll
    for (int g = 0; g < 2; g++) {
#pragma unroll
        for (int tt = 0; tt < 2; tt++) {
            const int tile = g * 2 + tt;
            int py = wi * 8 + tile * 2 + (lm >> 3);
            int px = wj * 8 + (lm & 7);
            const bf16_t* kp = qkvs + (size_t)(py * 256 + px) * 288 + 96 + h * 16;
            short8 kf = {};
            float kn2 = 0.f;
            float klo[4], khi[4];
            if (lq < 2) {
                uint4 kr = *(const uint4*)(kp + lq * 8);
                unsigned ku[4] = {kr.x, kr.y, kr.z, kr.w};
#pragma unroll
                for (int j2 = 0; j2 < 4; j2++) {
                    klo[j2] = __uint_as_float(ku[j2] << 16);
                    khi[j2] = __uint_as_float(ku[j2] & 0xffff0000u);
                    kn2 += klo[j2] * klo[j2] + khi[j2] * khi[j2];
                }
            }
            kn2 += __shfl_xor(kn2, 16, 64);
            kn2 += __shfl_xor(kn2, 32, 64);
            float rk = 1.0f / fmaxf(sqrtf(kn2), 1e-12f);
            if (lq < 2) {
                unsigned* kuo = (unsigned*)&kf;
#pragma unroll
                for (int j2 = 0; j2 < 4; j2++)
                    kuo[j2] = pk2(klo[j2] * rk, khi[j2] * rk);
            }
            f32x4 s = __builtin_amdgcn_mfma_f32_16x16x32_bf16(kf, af, zz, 0, 0, 0);
            float e[4];
#pragma unroll
            for (int r = 0; r < 4; r++) {
                e[r] = __expf(fmaf(s[r], sa,
                              bT_s[((tile * 16 + lq * 4 + r) << 4) + lm]));
                sum += e[r];
            }
            P_s[wv][lm][tile * 8 + lq * 2]     = pk2(e[0], e[1]);
            P_s[wv][lm][tile * 8 + lq * 2 + 1] = pk2(e[2], e[3]);
        }
        // ---- PV for keys g*32 .. g*32+31 ----
        const short8 pf = *(const short8*)&P_s[wv][lm][g * 16 + lq * 4];
        short8 vf;
        int pyv = wi * 8 + g * 4 + lq;
        const bf16_t* vrow = qkvs + (size_t)(pyv * 256 + wj * 8) * 288 + 192 + h * 16 + lm;
#pragma unroll
        for (int i = 0; i < 8; i++)
            ((bf16_t*)&vf)[i] = vrow[(size_t)i * 288];
        o = __builtin_amdgcn_mfma_f32_16x16x32_bf16(pf, vf, o, 0, 0, 0);
    }

    sum += __shfl_xor(sum, 16, 64);
    sum += __shfl_xor(sum, 32, 64);
    const float inv = 1.0f / sum;
    float* xp = x1 + ((size_t)w * 6 + h) * 256;
#pragma unroll
    for (int r = 0; r < 4; r++) {
        float iv = __shfl(inv, lq * 4 + r, 64);   // inv for anchor lq*4+r
        xp[(lq * 4 + r) * 16 + lm] = o[r] * iv;
    }
}

// Stripe stage 2 -> cat[:, 96:192] (bf16), window-reversed
__global__ __launch_bounds__(256) void attn2_k(
    const float* __restrict__ apw,
    const bf16_t* __restrict__ qkvs,
    const float* __restrict__ b2p,    // (6,1024): [h][n1*16+m]
    const float* __restrict__ ls2,
    const float* __restrict__ x1,
    bf16_t* __restrict__ cat)         // (65536,192) bf16, cols 96..191
{
    int tid = blockIdx.x * 256 + threadIdx.x;
    if (tid >= 1024 * 6 * 64) return;
    int n1 = tid & 63;
    int h = (tid >> 6) % 6;
    int w = tid / 384;
    int wi = w >> 5, wj = w & 31;
    float scale = __expf(fminf(ls2[h], 4.605170185988091f));

    int qy = wi * 8 + (n1 >> 3), qx = wj * 8 + (n1 & 7);
    const bf16_t* qp = qkvs + (size_t)(qy * 256 + qx) * 288 + h * 16;
    float qv[16];
    ld_bf8(qp, qv); ld_bf8(qp + 8, qv + 8);
    float nrm = 0.f;
#pragma unroll
    for (int d = 0; d < 16; d++) nrm += qv[d] * qv[d];
    float innorm = 1.0f / fmaxf(sqrtf(nrm), 1e-12f);
#pragma unroll
    for (int d = 0; d < 16; d++) qv[d] *= innorm;

    const float* bp = b2p + h * 1024 + n1 * 16;
    float sum = 0.f;
    float acc[16] = {};
#pragma unroll
    for (int m = 0; m < 16; m++) {
        int ay = wi * 4 + (m >> 2), ax = wj * 4 + (m & 3);
        const float* ap = apw + (size_t)(ay * 128 + ax) * 96 + h * 16;
        float dot = 0.f, kn = 0.f;
#pragma unroll
        for (int d = 0; d < 16; d += 4) {
            float4 v = *(const float4*)(ap + d);
            dot += qv[d] * v.x + qv[d + 1] * v.y + qv[d + 2] * v.z + qv[d + 3] * v.w;
            kn += v.x * v.x + v.y * v.y + v.z * v.z + v.w * v.w;
        }
        dot *= 1.0f / fmaxf(sqrtf(kn), 1e-12f);
        float e = __expf(fmaf(dot, scale, bp[m]));
        sum += e;
        const float* vp = x1 + ((size_t)w * 6 + h) * 256 + m * 16;
#pragma unroll
        for (int d = 0; d < 16; d += 4) {
            float4 v = *(const float4*)(vp + d);
            acc[d] += e * v.x; acc[d + 1] += e * v.y;
            acc[d + 2] += e * v.z; acc[d + 3] += e * v.w;
        }
    }
    float inv = 1.0f / sum;
#pragma unroll
    for (int d = 0; d < 16; d++) acc[d] *= inv;
    bf16_t* op = cat + (size_t)(qy * 256 + qx) * 192 + 96 + h * 16;
    uint4 o0, o1;
    o0.x = pk2(acc[0], acc[1]);   o0.y = pk2(acc[2], acc[3]);
    o0.z = pk2(acc[4], acc[5]);   o0.w = pk2(acc[6], acc[7]);
    o1.x = pk2(acc[8], acc[9]);   o1.y = pk2(acc[10], acc[11]);
    o1.z = pk2(acc[12], acc[13]); o1.w = pk2(acc[14], acc[15]);
    *(uint4*)(op) = o0;
    *(uint4*)(op + 8) = o1;
}

extern "C" void kernel_launch(void* const* d_in, const int* in_sizes, int n_in,
                              void* d_out, int out_size, void* d_ws, size_t ws_size,
                              hipStream_t stream) {
    const float* x          = (const float*)d_in[0];
    const float* table      = (const float*)d_in[3];
    const int*   idx_a2w    = (const int*)d_in[4];
    const int*   idx_w2a    = (const int*)d_in[5];
    const float* qkv_w      = (const float*)d_in[6];
    const float* qkv_b      = (const float*)d_in[7];
    const float* adw_w      = (const float*)d_in[8];
    const float* adw_b      = (const float*)d_in[9];
    const float* apw_w      = (const float*)d_in[10];
    const float* apw_b      = (const float*)d_in[11];
    const float* na_qkv_w   = (const float*)d_in[12];
    const float* na_qkv_b   = (const float*)d_in[13];
    const float* na_after_w = (const float*)d_in[14];
    const float* na_after_b = (const float*)d_in[15];
    const float* na_rpb     = (const float*)d_in[16];
    const float* ls1        = (const float*)d_in[17];
    const float* cpb1_w1    = (const float*)d_in[18];
    const float* cpb1_b1    = (const float*)d_in[19];
    const float* cpb1_w2    = (const float*)d_in[20];
    const float* ls2        = (const float*)d_in[21];
    const float* cpb2_w1    = (const float*)d_in[22];
    const float* cpb2_b1    = (const float*)d_in[23];
    const float* cpb2_w2    = (const float*)d_in[24];
    const float* proj_w     = (const float*)d_in[25];
    const float* proj_b     = (const float*)d_in[26];
    float* out = (float*)d_out;
    (void)in_sizes; (void)n_in; (void)out_size; (void)ws_size;

    // ---- byte-based workspace allocator (256B aligned) ----
    char* base = (char*)d_ws;
    size_t off = 0;
    auto alloc = [&](size_t bytes) {
        off = (off + 255) & ~(size_t)255;
        void* p = base + off; off += bytes; return p;
    };
    float*  bna    = (float*)alloc(576 * 4);
    float*  bt1    = (float*)alloc(225 * 6 * 4);
    float*  bt2    = (float*)alloc(225 * 6 * 4);
    float*  b1pT   = (float*)alloc(6144 * 4);
    float*  b2p    = (float*)alloc(6144 * 4);
    float*  qkv_wT = (float*)alloc(288 * 192 * 4);
    bf16_t* Wna_t  = (bf16_t*)alloc(576 * 192 * 2);
    bf16_t* Ws_t   = (bf16_t*)alloc(288 * 192 * 2);
    bf16_t* Waft_t = (bf16_t*)alloc(96 * 192 * 2);
    bf16_t* Wproj_t= (bf16_t*)alloc(192 * 192 * 2);
    bf16_t* qkvs   = (bf16_t*)alloc((size_t)65536 * 288 * 2);  // 37.75 MB
    char*   naR    = (char*)alloc((size_t)65536 * 576 * 2);    // 75.5 MB region
    char*   R      = (char*)alloc((size_t)65536 * 192 * 2);    // 25.2 MB region
    float*  apw    = (float*)alloc((size_t)16384 * 96 * 4);    // 6.3 MB
    // region aliases (strictly sequential lifetimes on the in-order stream):
    bf16_t* naqkv   = (bf16_t*)naR;               // naqkv gemm .. na_attn (planes)
    float*  x1      = (float*)naR;                // attn1 .. attn2 (6.3 MB)
    bf16_t* cat     = (bf16_t*)(naR + (8 << 20)); // na_after .. proj (25.2 MB)
    bf16_t* xb      = (bf16_t*)R;                 // cvt .. naqkv gemm (25.2 MB)
    float*  adw     = (float*)R;                  // dwconv .. apw gemm (12.6 MB)
    bf16_t* xna_pre = (bf16_t*)R;                 // na_attn .. na_after (25.2 MB)
    // VT planes (24 MiB) live in d_out-as-scratch: out is only written by the
    // final proj gemm, which fully overwrites it.
    bf16_t* vt      = (bf16_t*)out;               // vtpose .. na_attn

    // Tiny precomputes (independent)
    tpose_qkvw_k<<<216, 256, 0, stream>>>(qkv_w, qkv_wT);
    fold_wna_t_k<<<432, 256, 0, stream>>>(qkv_wT, na_qkv_w, Wna_t);
    fold_bna_k<<<3, 256, 0, stream>>>(qkv_b, na_qkv_w, na_qkv_b, bna);
    cpb_k<<<6, 256, 0, stream>>>(table, cpb1_w1, cpb1_b1, cpb1_w2, bt1);
    cpb_k<<<6, 256, 0, stream>>>(table, cpb2_w1, cpb2_b1, cpb2_w2, bt2);
    sigb1T_k<<<24, 256, 0, stream>>>(bt1, idx_a2w, b1pT);
    sigb_k<<<24, 256, 0, stream>>>(bt2, idx_w2a, b2p);
    tcvt_k<<<216, 256, 0, stream>>>(qkv_w, Ws_t, 192, 288, 576, 288);
    tcvt_k<<<72, 256, 0, stream>>>(na_after_w, Waft_t, 192, 96, 96, 0);
    tcvt_k<<<144, 256, 0, stream>>>(proj_w, Wproj_t, 192, 192, 192, 0);
    cvt_bf16_k<<<6144, 256, 0, stream>>>(x, xb, 65536 * 192 / 8);

    // Stripe qkv: xb @ Ws_t^T + b -> qkvs bf16 (65536,288), row-major
    mfma_gemm_k<192, 0, 3, bf16_t><<<1536, 256, 0, stream>>>(
        xb, Ws_t, qkv_b + 288, qkvs, 192, 192, 288);

    // Folded NA qkv: xb @ Wna_t^T + bna -> naqkv (Q/K/V planes, coalesced)
    mfma_gemm_k<192, 1, 6, bf16_t><<<3072, 256, 0, stream>>>(
        xb, Wna_t, bna, naqkv, 192, 192, 576);

    // Anchor: depthwise conv (xb dead -> adw in R), pointwise GEMM -> apw
    dwconv_k<<<3072, 256, 0, stream>>>(x, adw_w, adw_b, adw);
    gemm_k<float, float><<<dim3(2, 256), 256, 0, stream>>>(
        adw, apw_w, apw_b, apw, 16384, 96, 192, 192, 96, 96);

    // V planes -> VT planes (scratch in d_out), XCD-aligned with na_attn and
    // launched right before it so VT is L2-hot per XCD.
    vtpose_k<<<3072, 256, 0, stream>>>(naqkv, vt);

    // Neighborhood attention (adw dead -> xna_pre in R)
    na_attn_k<<<6144, 256, 0, stream>>>(naqkv, vt, na_rpb, xna_pre);

    // na_after: xna_pre @ Waft_t^T + b -> cat[:,0:96]  (naqkv dead)
    mfma_gemm_k<192, 0, 1, bf16_t><<<512, 256, 0, stream>>>(
        xna_pre, Waft_t, na_after_b, cat, 192, 192, 192);

    // Stripe attention -> x1, then cat[:,96:192]
    attn1_k<<<dim3(256, 6), 256, 0, stream>>>(apw, qkvs, b1pT, ls1, x1);
    attn2_k<<<1536, 256, 0, stream>>>(apw, qkvs, b2p, ls2, x1, cat);

    // Final projection: cat @ Wproj_t^T + proj_b -> out fp32 (vt dead)
    mfma_gemm_k<192, 0, 2, float><<<1024, 256, 0, stream>>>(
        cat, Wproj_t, proj_b, out, 192, 192, 192);
}

// Round 8
// 576.425 us; speedup vs baseline: 1.0783x; 1.0738x over previous
//
#include <hip/hip_runtime.h>
#include <math.h>

// ---------------------------------------------------------------------------
// MixedAttention: H=W=256, C=192, HEADS=6, NA: K=7 DIL=2 hd=32,
// stripe: WS=8 AWS=4 hs=16, 1024 windows.
// R15: NA-qkv GEMM LDS-repack epilogue. The old NA=1 epilogue issued 48
// scattered 2B stores/thread into parity planes (write-allocate thrash,
// 64 txns/wave). Now: stage the block's 128x96 tile in LDS (26.6KB,
// stride 104 = 16B-aligned, <=4-way write conflicts), then write out as
// 3 heads x 2 parities x 64-consecutive-pixel CONTIGUOUS segments:
// Q/K -> 4KB uint4-coalesced plane segments; V -> VT [d][pix] 128B
// segments written DIRECTLY (vtpose_k kernel deleted, -48MB traffic).
// Bit-exact vs R14 (same f2bf values, same final addresses).
// na_attn unchanged (R14 body, 89us known).
// ---------------------------------------------------------------------------

typedef unsigned short bf16_t;
typedef __attribute__((ext_vector_type(8))) short short8;   // MFMA A/B frag (8 bf16)
typedef __attribute__((ext_vector_type(4))) float f32x4;    // MFMA C/D frag

__device__ inline float bf2f(bf16_t v) { return __uint_as_float((unsigned)v << 16); }
__device__ inline bf16_t f2bf(float f) {
    unsigned u = __float_as_uint(f);
    unsigned r = (u + 0x7fffu + ((u >> 16) & 1u)) >> 16;   // RNE, finite inputs
    return (bf16_t)r;
}
__device__ inline float cvt(float v) { return v; }
__device__ inline float cvt(bf16_t v) { return bf2f(v); }
__device__ inline void sto(float* p, float v) { *p = v; }
__device__ inline void sto(bf16_t* p, float v) { *p = f2bf(v); }

// load 8 consecutive bf16 (16B aligned) -> 8 floats
__device__ inline void ld_bf8(const bf16_t* p, float* d) {
    uint4 r = *(const uint4*)p;
    d[0] = __uint_as_float(r.x << 16); d[1] = __uint_as_float(r.x & 0xffff0000u);
    d[2] = __uint_as_float(r.y << 16); d[3] = __uint_as_float(r.y & 0xffff0000u);
    d[4] = __uint_as_float(r.z << 16); d[5] = __uint_as_float(r.z & 0xffff0000u);
    d[6] = __uint_as_float(r.w << 16); d[7] = __uint_as_float(r.w & 0xffff0000u);
}
__device__ inline unsigned pk2(float a, float b) {
    return (unsigned)f2bf(a) | ((unsigned)f2bf(b) << 16);
}

// ---------------------------------------------------------------------------
// MFMA GEMM: C[M,N] = A[M,K]bf16 @ Bt[N,K]^T + bias. Tile 128x96, 4 waves,
// each wave 64x48 = 4x3 16x16 frags, K=192 fully unrolled.
// 1D grid (multiple of 8) with bijective XCD chunk swizzle; NCOL = column
// tiles per row so each XCD owns contiguous rows x all cols (A L2 reuse).
// NA=1: LDS repack epilogue -> coalesced plane segments + direct VT.
//   Q/K planes (C): ((which*6+h)*65536 + par*16384 + pixin)*32 + d
//   VT planes (C2): (h*4+par)*524288 + d*16384 + pixin
// ---------------------------------------------------------------------------
template <int KD, int NA, int NCOL, typename TO>
__global__ __launch_bounds__(256) void mfma_gemm_k(
    const bf16_t* __restrict__ A, const bf16_t* __restrict__ Bt,
    const float* __restrict__ bias, TO* __restrict__ C,
    bf16_t* __restrict__ C2,
    int lda, int ldb, int ldc)
{
    __shared__ bf16_t Cs[NA ? 128 : 1][NA ? 104 : 1];

    const int bid  = blockIdx.x;
    const int work = (bid & 7) * (gridDim.x >> 3) + (bid >> 3);
    const int brow = work / NCOL;
    const int bcol = work - brow * NCOL;

    const int t = threadIdx.x;
    const int lane = t & 63, wave = t >> 6;
    const int wr = wave >> 1, wc = wave & 1;
    const int m0 = brow * 128 + wr * 64;
    const int n0 = bcol * 96 + wc * 48;
    const int lm = lane & 15;
    const int q  = lane >> 4;

    f32x4 acc[4][3] = {};
    const bf16_t* ap = A + (size_t)(m0 + lm) * lda + q * 8;
    const bf16_t* bp = Bt + (size_t)(n0 + lm) * ldb + q * 8;

#pragma unroll
    for (int k0 = 0; k0 < KD; k0 += 32) {
        short8 af[4], bf[3];
#pragma unroll
        for (int mi = 0; mi < 4; mi++)
            af[mi] = *(const short8*)(ap + (size_t)(mi * 16) * lda + k0);
#pragma unroll
        for (int ni = 0; ni < 3; ni++)
            bf[ni] = *(const short8*)(bp + (size_t)(ni * 16) * ldb + k0);
#pragma unroll
        for (int mi = 0; mi < 4; mi++)
#pragma unroll
            for (int ni = 0; ni < 3; ni++)
                acc[mi][ni] = __builtin_amdgcn_mfma_f32_16x16x32_bf16(
                    af[mi], bf[ni], acc[mi][ni], 0, 0, 0);
    }

    if (NA) {
        // ---- stage tile in LDS (local coords) ----
#pragma unroll
        for (int mi = 0; mi < 4; mi++) {
#pragma unroll
            for (int ni = 0; ni < 3; ni++) {
                int lcol = wc * 48 + ni * 16 + lm;
                float bv = bias[bcol * 96 + lcol];
#pragma unroll
                for (int r = 0; r < 4; r++) {
                    int lrow = wr * 64 + mi * 16 + q * 4 + r;
                    Cs[lrow][lcol] = f2bf(acc[mi][ni][r] + bv);
                }
            }
        }
        __syncthreads();

        const int which = bcol >> 1;          // 0=Q 1=K 2=V
        const int hh0   = (bcol & 1) * 3;     // head base within which
        const int gi    = (brow >> 1) & 1;
        const int pixbase = (brow >> 2) * 128 + (brow & 1) * 64;

        if (which < 2) {
            // 6 segments (hh_l x gj), each 64px x 32d = 4KB contiguous
            const int px = t >> 2, d8 = (t & 3) << 3;
#pragma unroll
            for (int hh_l = 0; hh_l < 3; hh_l++) {
#pragma unroll
                for (int gj = 0; gj < 2; gj++) {
                    int par = gi * 2 + gj;
                    bf16_t* dst = (bf16_t*)C
                        + (size_t)(which * 6 + hh0 + hh_l) * 2097152
                        + ((size_t)(par * 16384 + pixbase) << 5);
                    uint4 v = *(const uint4*)&Cs[2 * px + gj][hh_l * 32 + d8];
                    *(uint4*)(dst + px * 32 + d8) = v;
                }
            }
        } else {
            // VT: 192 segments (hh_l x d x gj), each 64px = 128B; 8 thr/seg
#pragma unroll
            for (int rd = 0; rd < 6; rd++) {
                int task = rd * 256 + t;       // 0..1535
                int seg  = task >> 3;          // 0..191
                int px8  = (task & 7) << 3;    // 0..56
                int hh_l = seg / 64;
                int rem  = seg - hh_l * 64;
                int d    = rem >> 1;
                int gj   = rem & 1;
                int par  = gi * 2 + gj;
                unsigned short buf[8];
#pragma unroll
                for (int i = 0; i < 8; i++)
                    buf[i] = Cs[2 * (px8 + i) + gj][hh_l * 32 + d];
                bf16_t* dst = C2
                    + (((size_t)(hh0 + hh_l) * 4 + par) << 19)
                    + ((size_t)d << 14) + pixbase + px8;
                *(uint4*)dst = *(uint4*)buf;
            }
        }
    } else {
#pragma unroll
        for (int mi = 0; mi < 4; mi++) {
#pragma unroll
            for (int ni = 0; ni < 3; ni++) {
                int col = n0 + ni * 16 + lm;
                float bv = bias[col];
#pragma unroll
                for (int r = 0; r < 4; r++) {
                    int row = m0 + mi * 16 + q * 4 + r;
                    sto(&C[(size_t)row * ldc + col], acc[mi][ni][r] + bv);
                }
            }
        }
    }
}

// x fp32 -> bf16, 8 elems/thread
__global__ __launch_bounds__(256) void cvt_bf16_k(
    const float* __restrict__ src, bf16_t* __restrict__ dst, int n8)
{
    int tid = blockIdx.x * 256 + threadIdx.x;
    if (tid >= n8) return;
    float4 a = ((const float4*)src)[tid * 2];
    float4 b = ((const float4*)src)[tid * 2 + 1];
    uint4 o;
    o.x = pk2(a.x, a.y); o.y = pk2(a.z, a.w);
    o.z = pk2(b.x, b.y); o.w = pk2(b.z, b.w);
    ((uint4*)dst)[tid] = o;
}

// Wt[n*Kd + k] = (bf16) W[k*ld + coloff + n]   (transpose + convert)
__global__ __launch_bounds__(256) void tcvt_k(
    const float* __restrict__ W, bf16_t* __restrict__ Wt,
    int Kd, int N, int ld, int coloff)
{
    int tid = blockIdx.x * 256 + threadIdx.x;
    if (tid >= Kd * N) return;
    int k = tid % Kd, n = tid / Kd;
    Wt[tid] = f2bf(W[(size_t)k * ld + coloff + n]);
}

// qkv_wT[j*192 + k] = qkv_w[k*576 + j], j < 288
__global__ __launch_bounds__(256) void tpose_qkvw_k(
    const float* __restrict__ W, float* __restrict__ WT)
{
    int tid = blockIdx.x * 256 + threadIdx.x;
    if (tid >= 288 * 192) return;
    int k = tid % 192, j = tid / 192;
    WT[tid] = W[(size_t)k * 576 + j];
}

// Wna_t[n*192 + k] = (bf16) sum_j qkv_wT[j,k] * na_qkv_w[j,n], j<288
__global__ __launch_bounds__(256) void fold_wna_t_k(
    const float* __restrict__ qkv_wT, const float* __restrict__ na_qkv_w,
    bf16_t* __restrict__ Wna_t)
{
    int tid = blockIdx.x * 256 + threadIdx.x;
    if (tid >= 576 * 192) return;
    int k = tid % 192, n = tid / 192;
    float acc = 0.f;
    for (int j = 0; j < 288; j++)
        acc += qkv_wT[j * 192 + k] * na_qkv_w[j * 576 + n];
    Wna_t[tid] = f2bf(acc);
}

__global__ __launch_bounds__(256) void fold_bna_k(
    const float* __restrict__ qkv_b, const float* __restrict__ na_qkv_w,
    const float* __restrict__ na_qkv_b, float* __restrict__ bna)
{
    int j = blockIdx.x * 256 + threadIdx.x;
    if (j >= 576) return;
    float acc = na_qkv_b[j];
    for (int k = 0; k < 288; k++)
        acc += qkv_b[k] * na_qkv_w[k * 576 + j];
    bna[j] = acc;
}

// bt[t,h] = (relu(table(225,2) @ w1 + b1) @ w2)[t,h]
__global__ __launch_bounds__(256) void cpb_k(
    const float* __restrict__ table, const float* __restrict__ w1,
    const float* __restrict__ b1, const float* __restrict__ w2,
    float* __restrict__ bt)
{
    int tid = blockIdx.x * 256 + threadIdx.x;
    if (tid >= 225 * 6) return;
    int h = tid % 6, t = tid / 6;
    float t0 = table[t * 2], t1 = table[t * 2 + 1];
    float acc = 0.f;
    for (int m = 0; m < 512; m++) {
        float hv = t0 * w1[m] + t1 * w1[512 + m] + b1[m];
        hv = fmaxf(hv, 0.f);
        acc += hv * w2[m * 6 + h];
    }
    bt[tid] = acc;
}

// b2p[h*1024 + n1*16 + m] = 16*sigmoid(bt[idx[n1*16+m]*6 + h])  (attn2)
__global__ __launch_bounds__(256) void sigb_k(
    const float* __restrict__ bt, const int* __restrict__ idx,
    float* __restrict__ bp)
{
    int tid = blockIdx.x * 256 + threadIdx.x;
    if (tid >= 6144) return;
    int h = tid >> 10, p = tid & 1023;
    bp[tid] = 16.0f / (1.0f + __expf(-bt[idx[p] * 6 + h]));
}

// b1pT[h*1024 + m*16 + n2] = 16*sigmoid(bt[idx[n2*64+m]*6 + h])  (attn1)
__global__ __launch_bounds__(256) void sigb1T_k(
    const float* __restrict__ bt, const int* __restrict__ idx,
    float* __restrict__ bp)
{
    int tid = blockIdx.x * 256 + threadIdx.x;
    if (tid >= 6144) return;
    int h = tid >> 10, p = tid & 1023;
    int m = p >> 4, n2 = p & 15;
    bp[tid] = 16.0f / (1.0f + __expf(-bt[idx[n2 * 64 + m] * 6 + h]));
}

// legacy fp32 tiled GEMM (kept for the small anchor-pointwise GEMM)
#define BM 64
#define BN 64
#define BKK 16
template <typename TA, typename TO>
__global__ __launch_bounds__(256) void gemm_k(
    const TA* __restrict__ A, const float* __restrict__ B,
    const float* __restrict__ bias, TO* __restrict__ C,
    int M, int N, int Kd, int lda, int ldb, int ldc)
{
    __shared__ float As[BKK][BM + 1];
    __shared__ float Bs[BKK][BN + 1];
    const int t  = threadIdx.x;
    const int tx = t & 15, ty = t >> 4;
    const int m0 = blockIdx.y * BM, n0 = blockIdx.x * BN;
    float acc[4][4] = {};

    for (int k0 = 0; k0 < Kd; k0 += BKK) {
#pragma unroll
        for (int i = 0; i < 4; i++) {
            int m = (t >> 4) + i * 16;
            int k = t & 15;
            int gm = m0 + m, gk = k0 + k;
            As[k][m] = (gm < M && gk < Kd) ? cvt(A[(size_t)gm * lda + gk]) : 0.f;
        }
#pragma unroll
        for (int i = 0; i < 4; i++) {
            int k = (t >> 6) + i * 4;
            int n = t & 63;
            int gk = k0 + k, gn = n0 + n;
            Bs[k][n] = (gk < Kd && gn < N) ? B[(size_t)gk * ldb + gn] : 0.f;
        }
        __syncthreads();
#pragma unroll
        for (int k = 0; k < BKK; k++) {
            float a[4], b[4];
#pragma unroll
            for (int i = 0; i < 4; i++) a[i] = As[k][ty * 4 + i];
#pragma unroll
            for (int j = 0; j < 4; j++) b[j] = Bs[k][tx * 4 + j];
#pragma unroll
            for (int i = 0; i < 4; i++)
#pragma unroll
                for (int j = 0; j < 4; j++) acc[i][j] += a[i] * b[j];
        }
        __syncthreads();
    }
#pragma unroll
    for (int i = 0; i < 4; i++) {
        int gm = m0 + ty * 4 + i;
        if (gm >= M) continue;
#pragma unroll
        for (int j = 0; j < 4; j++) {
            int gn = n0 + tx * 4 + j;
            if (gn >= N) continue;
            sto(&C[(size_t)gm * ldc + gn], acc[i][j] + bias[gn]);
        }
    }
}

// Depthwise 3x3 stride-2 pad-1 on x (256,256,192) -> adw (128,128,192) fp32
__global__ __launch_bounds__(256) void dwconv_k(
    const float* __restrict__ x, const float* __restrict__ w,
    const float* __restrict__ b, float* __restrict__ adw)
{
    int tid = blockIdx.x * 256 + threadIdx.x;
    if (tid >= 16384 * 48) return;
    int c4 = tid % 48;
    int p = tid / 48;
    int ow = p & 127, oh = p >> 7;
    int c = c4 * 4;
    float4 s = *(const float4*)(b + c);
#pragma unroll
    for (int kh = 0; kh < 3; kh++) {
        int ih = oh * 2 - 1 + kh;
        if (ih < 0 || ih >= 256) continue;
#pragma unroll
        for (int kw = 0; kw < 3; kw++) {
            int iw = ow * 2 - 1 + kw;
            if (iw < 0 || iw >= 256) continue;
            float4 xv = *(const float4*)(x + (size_t)(ih * 256 + iw) * 192 + c);
            float4 wv = *(const float4*)(w + (kh * 3 + kw) * 192 + c);
            s.x += xv.x * wv.x; s.y += xv.y * wv.y;
            s.z += xv.z * wv.z; s.w += xv.w * wv.w;
        }
    }
    *(float4*)(adw + (size_t)p * 192 + c) = s;
}

// ---------------------------------------------------------------------------
// Neighborhood attention (R14 body, 89us known-good).
// grid 6144 (XCD-chunked), block 256 = 4 waves.
// ---------------------------------------------------------------------------
__global__ __launch_bounds__(256) void na_attn_k(
    const bf16_t* __restrict__ nap, const bf16_t* __restrict__ vt,
    const float* __restrict__ rpb, bf16_t* __restrict__ outp)
{
    __shared__ float rpb_s[176];
    __shared__ __align__(16) unsigned P_s[4][16][20];   // [wave][q][slot-pair]

    const int bid  = blockIdx.x;
    const int work = (bid & 7) * 768 + (bid >> 3);
    const int z    = work >> 8;          // 0..23 : h*4+par
    const int rem  = work & 255;
    const int pi   = rem >> 1;
    const int xh   = rem & 1;

    const int t = threadIdx.x;
    const int wv = t >> 6, lane = t & 63;
    const int lm = lane & 15, lq = lane >> 4;
    const int h = z >> 2, par = z & 3;

    if (t < 169) rpb_s[t] = rpb[h * 169 + t];
    __syncthreads();

    const int pj0 = xh * 64 + wv * 16;
    const int si  = min(max(pi - 3, 0), 121);
    const int rbh0 = si - pi + 6;
    const int c0  = min(max(pj0 - 3, 0), 121) & ~7;

    const size_t plane = (size_t)65536 * 32;
    const size_t poff  = (size_t)(par * 16384) * 32;
    const bf16_t* qpl = nap + (size_t)h * plane + poff;
    const bf16_t* kpl = nap + (size_t)(6 + h) * plane + poff;
    const bf16_t* vtpl = vt + ((size_t)z << 19);        // [d][pix]

    const short8 qf = *(const short8*)(qpl + ((size_t)(pi * 128 + pj0 + lm)) * 32 + lq * 8);

    int offc[4][2]; bool vm[4][2];
#pragma unroll
    for (int r = 0; r < 4; r++) {
        int q = lq * 4 + r, pj = pj0 + q;
        int sj = min(max(pj - 3, 0), 121);
#pragma unroll
        for (int t2 = 0; t2 < 2; t2++) {
            int c = c0 + 2 * lm + t2;
            vm[r][t2] = (c >= sj) && (c <= sj + 6);
            offc[r][t2] = min(max(c - pj + 6, 0), 12);
        }
    }
    const int kc0 = min(c0 + 2 * lm,     127) * 64;   // byte offsets (64B/px)
    const int kc1 = min(c0 + 2 * lm + 1, 127) * 64;
    const int vcol = c0 + (lq << 3);
    const size_t vb0 = (size_t)lm * 16384;            // d = lm
    const size_t vb1 = (size_t)(lm + 16) * 16384;     // d = 16+lm

    const float scale = 0.17677669529663687f; // 32^-0.5
    f32x4 o0 = {}, o1 = {};
    float sums[4] = {0.f, 0.f, 0.f, 0.f};
    const f32x4 zz = {};

#pragma unroll
    for (int rr = 0; rr < 7; rr++) {
        const char* krow = (const char*)kpl + (size_t)((si + rr) * 128) * 64;

        short8 kf0 = *(const short8*)(krow + kc0 + lq * 16);
        short8 kf1 = *(const short8*)(krow + kc1 + lq * 16);
        f32x4 s0 = __builtin_amdgcn_mfma_f32_16x16x32_bf16(qf, kf0, zz, 0, 0, 0);
        f32x4 s1 = __builtin_amdgcn_mfma_f32_16x16x32_bf16(qf, kf1, zz, 0, 0, 0);

        const float* br = rpb_s + (rbh0 + rr) * 13;
        float e0[4], e1[4];
#pragma unroll
        for (int r = 0; r < 4; r++) {
            float a0 = __expf(fmaf(s0[r], scale, br[offc[r][0]]));
            float a1 = __expf(fmaf(s1[r], scale, br[offc[r][1]]));
            a0 = vm[r][0] ? a0 : 0.f;
            a1 = vm[r][1] ? a1 : 0.f;
            e0[r] = a0; e1[r] = a1;
            sums[r] += a0 + a1;
        }
#pragma unroll
        for (int r = 0; r < 4; r++) {
            unsigned pr;
            asm("v_cvt_pk_bf16_f32 %0, %1, %2" : "=v"(pr) : "v"(e0[r]), "v"(e1[r]));
            P_s[wv][lq * 4 + r][lm] = pr;   // slots 2lm (lo), 2lm+1 (hi)
        }
        const short8 pf = *(const short8*)((const bf16_t*)P_s[wv][lm] + lq * 8);

        int rowo = min((si + rr) * 128 + vcol, 16376);
        short8 vf0 = *(const short8*)(vtpl + vb0 + rowo);
        short8 vf1 = *(const short8*)(vtpl + vb1 + rowo);

        o0 = __builtin_amdgcn_mfma_f32_16x16x32_bf16(pf, vf0, o0, 0, 0, 0);
        o1 = __builtin_amdgcn_mfma_f32_16x16x32_bf16(pf, vf1, o1, 0, 0, 0);
    }

#pragma unroll
    for (int r = 0; r < 4; r++) {
        float s = sums[r];
        s += __shfl_xor(s, 1, 64);
        s += __shfl_xor(s, 2, 64);
        s += __shfl_xor(s, 4, 64);
        s += __shfl_xor(s, 8, 64);
        sums[r] = 1.0f / s;
    }

    const int gi = par >> 1, gj = par & 1;
    const int i0 = pi * 2 + gi;
    bf16_t* ob = outp + ((size_t)i0 * 256 + gj) * 192 + h * 32 + lm;
#pragma unroll
    for (int r = 0; r < 4; r++) {
        int q = lq * 4 + r;
        size_t px = (size_t)(pj0 + q) * 2 * 192;
        ob[px]      = f2bf(o0[r] * sums[r]);
        ob[px + 16] = f2bf(o1[r] * sums[r]);
    }
}

// ---------------------------------------------------------------------------
// Stripe stage 1 v3 (MFMA): one wave = one (window, head). (verified R10)
// ---------------------------------------------------------------------------
__global__ __launch_bounds__(256) void attn1_k(
    const float* __restrict__ apw,    // (16384,96) fp32
    const bf16_t* __restrict__ qkvs,  // (65536,288) bf16
    const float* __restrict__ b1pT,   // (6,1024): [h][m*16+n2]
    const float* __restrict__ ls1,
    float* __restrict__ x1)           // (1024,6,16,16) fp32
{
    __shared__ float bT_s[1024];
    __shared__ __align__(16) unsigned P_s[4][16][36];

    const int t = threadIdx.x;
    const int wv = t >> 6, lane = t & 63;
    const int lm = lane & 15, lq = lane >> 4;
    const int h = blockIdx.y;
    const int w = blockIdx.x * 4 + wv;
    const int wi = w >> 5, wj = w & 31;

#pragma unroll
    for (int i = 0; i < 4; i++) bT_s[i * 256 + t] = b1pT[h * 1024 + i * 256 + t];
    __syncthreads();

    const float scale = __expf(fminf(ls1[h], 4.605170185988091f));

    // ---- anchors -> B-frag (col=anchor=lm, k=d=lq*8+i; d<16 so lq<2) ----
    short8 af = {};
    float an2 = 0.f;
    {
        int ay = wi * 4 + (lm >> 2), ax = wj * 4 + (lm & 3);
        const float* ap = apw + (size_t)(ay * 128 + ax) * 96 + h * 16;
        if (lq < 2) {
            float4 v0 = *(const float4*)(ap + lq * 8);
            float4 v1 = *(const float4*)(ap + lq * 8 + 4);
            float vs[8] = {v0.x, v0.y, v0.z, v0.w, v1.x, v1.y, v1.z, v1.w};
            unsigned* au = (unsigned*)&af;
#pragma unroll
            for (int j2 = 0; j2 < 4; j2++) {
                unsigned u = pk2(vs[2 * j2], vs[2 * j2 + 1]);
                au[j2] = u;
                float lo = __uint_as_float(u << 16);
                float hi = __uint_as_float(u & 0xffff0000u);
                an2 += lo * lo + hi * hi;   // norm of the ROUNDED anchor
            }
        }
    }
    an2 += __shfl_xor(an2, 16, 64);
    an2 += __shfl_xor(an2, 32, 64);
    const float sa = scale / fmaxf(sqrtf(an2), 1e-12f);  // fold anchor norm

    const f32x4 zz = {};
    f32x4 o = {};
    float sum = 0.f;

#pragma unroll
    for (int g = 0; g < 2; g++) {
#pragma unroll
        for (int tt = 0; tt < 2; tt++) {
            const int tile = g * 2 + tt;
            int py = wi * 8 + tile * 2 + (lm >> 3);
            int px = wj * 8 + (lm & 7);
            const bf16_t* kp = qkvs + (size_t)(py * 256 + px) * 288 + 96 + h * 16;
            short8 kf = {};
            float kn2 = 0.f;
            float klo[4], khi[4];
            if (lq < 2) {
                uint4 kr = *(const uint4*)(kp + lq * 8);
                unsigned ku[4] = {kr.x, kr.y, kr.z, kr.w};
#pragma unroll
                for (int j2 = 0; j2 < 4; j2++) {
                    klo[j2] = __uint_as_float(ku[j2] << 16);
                    khi[j2] = __uint_as_float(ku[j2] & 0xffff0000u);
                    kn2 += klo[j2] * klo[j2] + khi[j2] * khi[j2];
                }
            }
            kn2 += __shfl_xor(kn2, 16, 64);
            kn2 += __shfl_xor(kn2, 32, 64);
            float rk = 1.0f / fmaxf(sqrtf(kn2), 1e-12f);
            if (lq < 2) {
                unsigned* kuo = (unsigned*)&kf;
#pragma unroll
                for (int j2 = 0; j2 < 4; j2++)
                    kuo[j2] = pk2(klo[j2] * rk, khi[j2] * rk);
            }
            f32x4 s = __builtin_amdgcn_mfma_f32_16x16x32_bf16(kf, af, zz, 0, 0, 0);
            float e[4];
#pragma unroll
            for (int r = 0; r < 4; r++) {
                e[r] = __expf(fmaf(s[r], sa,
                              bT_s[((tile * 16 + lq * 4 + r) << 4) + lm]));
                sum += e[r];
            }
            P_s[wv][lm][tile * 8 + lq * 2]     = pk2(e[0], e[1]);
            P_s[wv][lm][tile * 8 + lq * 2 + 1] = pk2(e[2], e[3]);
        }
        // ---- PV for keys g*32 .. g*32+31 ----
        const short8 pf = *(const short8*)&P_s[wv][lm][g * 16 + lq * 4];
        short8 vf;
        int pyv = wi * 8 + g * 4 + lq;
        const bf16_t* vrow = qkvs + (size_t)(pyv * 256 + wj * 8) * 288 + 192 + h * 16 + lm;
#pragma unroll
        for (int i = 0; i < 8; i++)
            ((bf16_t*)&vf)[i] = vrow[(size_t)i * 288];
        o = __builtin_amdgcn_mfma_f32_16x16x32_bf16(pf, vf, o, 0, 0, 0);
    }

    sum += __shfl_xor(sum, 16, 64);
    sum += __shfl_xor(sum, 32, 64);
    const float inv = 1.0f / sum;
    float* xp = x1 + ((size_t)w * 6 + h) * 256;
#pragma unroll
    for (int r = 0; r < 4; r++) {
        float iv = __shfl(inv, lq * 4 + r, 64);   // inv for anchor lq*4+r
        xp[(lq * 4 + r) * 16 + lm] = o[r] * iv;
    }
}

// Stripe stage 2 -> cat[:, 96:192] (bf16), window-reversed
__global__ __launch_bounds__(256) void attn2_k(
    const float* __restrict__ apw,
    const bf16_t* __restrict__ qkvs,
    const float* __restrict__ b2p,    // (6,1024): [h][n1*16+m]
    const float* __restrict__ ls2,
    const float* __restrict__ x1,
    bf16_t* __restrict__ cat)         // (65536,192) bf16, cols 96..191
{
    int tid = blockIdx.x * 256 + threadIdx.x;
    if (tid >= 1024 * 6 * 64) return;
    int n1 = tid & 63;
    int h = (tid >> 6) % 6;
    int w = tid / 384;
    int wi = w >> 5, wj = w & 31;
    float scale = __expf(fminf(ls2[h], 4.605170185988091f));

    int qy = wi * 8 + (n1 >> 3), qx = wj * 8 + (n1 & 7);
    const bf16_t* qp = qkvs + (size_t)(qy * 256 + qx) * 288 + h * 16;
    float qv[16];
    ld_bf8(qp, qv); ld_bf8(qp + 8, qv + 8);
    float nrm = 0.f;
#pragma unroll
    for (int d = 0; d < 16; d++) nrm += qv[d] * qv[d];
    float innorm = 1.0f / fmaxf(sqrtf(nrm), 1e-12f);
#pragma unroll
    for (int d = 0; d < 16; d++) qv[d] *= innorm;

    const float* bp = b2p + h * 1024 + n1 * 16;
    float sum = 0.f;
    float acc[16] = {};
#pragma unroll
    for (int m = 0; m < 16; m++) {
        int ay = wi * 4 + (m >> 2), ax = wj * 4 + (m & 3);
        const float* ap = apw + (size_t)(ay * 128 + ax) * 96 + h * 16;
        float dot = 0.f, kn = 0.f;
#pragma unroll
        for (int d = 0; d < 16; d += 4) {
            float4 v = *(const float4*)(ap + d);
            dot += qv[d] * v.x + qv[d + 1] * v.y + qv[d + 2] * v.z + qv[d + 3] * v.w;
            kn += v.x * v.x + v.y * v.y + v.z * v.z + v.w * v.w;
        }
        dot *= 1.0f / fmaxf(sqrtf(kn), 1e-12f);
        float e = __expf(fmaf(dot, scale, bp[m]));
        sum += e;
        const float* vp = x1 + ((size_t)w * 6 + h) * 256 + m * 16;
#pragma unroll
        for (int d = 0; d < 16; d += 4) {
            float4 v = *(const float4*)(vp + d);
            acc[d] += e * v.x; acc[d + 1] += e * v.y;
            acc[d + 2] += e * v.z; acc[d + 3] += e * v.w;
        }
    }
    float inv = 1.0f / sum;
#pragma unroll
    for (int d = 0; d < 16; d++) acc[d] *= inv;
    bf16_t* op = cat + (size_t)(qy * 256 + qx) * 192 + 96 + h * 16;
    uint4 o0, o1;
    o0.x = pk2(acc[0], acc[1]);   o0.y = pk2(acc[2], acc[3]);
    o0.z = pk2(acc[4], acc[5]);   o0.w = pk2(acc[6], acc[7]);
    o1.x = pk2(acc[8], acc[9]);   o1.y = pk2(acc[10], acc[11]);
    o1.z = pk2(acc[12], acc[13]); o1.w = pk2(acc[14], acc[15]);
    *(uint4*)(op) = o0;
    *(uint4*)(op + 8) = o1;
}

extern "C" void kernel_launch(void* const* d_in, const int* in_sizes, int n_in,
                              void* d_out, int out_size, void* d_ws, size_t ws_size,
                              hipStream_t stream) {
    const float* x          = (const float*)d_in[0];
    const float* table      = (const float*)d_in[3];
    const int*   idx_a2w    = (const int*)d_in[4];
    const int*   idx_w2a    = (const int*)d_in[5];
    const float* qkv_w      = (const float*)d_in[6];
    const float* qkv_b      = (const float*)d_in[7];
    const float* adw_w      = (const float*)d_in[8];
    const float* adw_b      = (const float*)d_in[9];
    const float* apw_w      = (const float*)d_in[10];
    const float* apw_b      = (const float*)d_in[11];
    const float* na_qkv_w   = (const float*)d_in[12];
    const float* na_qkv_b   = (const float*)d_in[13];
    const float* na_after_w = (const float*)d_in[14];
    const float* na_after_b = (const float*)d_in[15];
    const float* na_rpb     = (const float*)d_in[16];
    const float* ls1        = (const float*)d_in[17];
    const float* cpb1_w1    = (const float*)d_in[18];
    const float* cpb1_b1    = (const float*)d_in[19];
    const float* cpb1_w2    = (const float*)d_in[20];
    const float* ls2        = (const float*)d_in[21];
    const float* cpb2_w1    = (const float*)d_in[22];
    const float* cpb2_b1    = (const float*)d_in[23];
    const float* cpb2_w2    = (const float*)d_in[24];
    const float* proj_w     = (const float*)d_in[25];
    const float* proj_b     = (const float*)d_in[26];
    float* out = (float*)d_out;
    (void)in_sizes; (void)n_in; (void)out_size; (void)ws_size;

    // ---- byte-based workspace allocator (256B aligned) ----
    char* base = (char*)d_ws;
    size_t off = 0;
    auto alloc = [&](size_t bytes) {
        off = (off + 255) & ~(size_t)255;
        void* p = base + off; off += bytes; return p;
    };
    float*  bna    = (float*)alloc(576 * 4);
    float*  bt1    = (float*)alloc(225 * 6 * 4);
    float*  bt2    = (float*)alloc(225 * 6 * 4);
    float*  b1pT   = (float*)alloc(6144 * 4);
    float*  b2p    = (float*)alloc(6144 * 4);
    float*  qkv_wT = (float*)alloc(288 * 192 * 4);
    bf16_t* Wna_t  = (bf16_t*)alloc(576 * 192 * 2);
    bf16_t* Ws_t   = (bf16_t*)alloc(288 * 192 * 2);
    bf16_t* Waft_t = (bf16_t*)alloc(96 * 192 * 2);
    bf16_t* Wproj_t= (bf16_t*)alloc(192 * 192 * 2);
    bf16_t* qkvs   = (bf16_t*)alloc((size_t)65536 * 288 * 2);  // 37.75 MB
    char*   naR    = (char*)alloc((size_t)65536 * 576 * 2);    // 75.5 MB region
    char*   R      = (char*)alloc((size_t)65536 * 192 * 2);    // 25.2 MB region
    float*  apw    = (float*)alloc((size_t)16384 * 96 * 4);    // 6.3 MB
    // region aliases (strictly sequential lifetimes on the in-order stream):
    bf16_t* naqkv   = (bf16_t*)naR;               // naqkv gemm .. na_attn (planes)
    float*  x1      = (float*)naR;                // attn1 .. attn2 (6.3 MB)
    bf16_t* cat     = (bf16_t*)(naR + (8 << 20)); // na_after .. proj (25.2 MB)
    bf16_t* xb      = (bf16_t*)R;                 // cvt .. naqkv gemm (25.2 MB)
    float*  adw     = (float*)R;                  // dwconv .. apw gemm (12.6 MB)
    bf16_t* xna_pre = (bf16_t*)R;                 // na_attn .. na_after (25.2 MB)
    // VT planes (24 MiB) live in d_out-as-scratch: out is only written by the
    // final proj gemm, which fully overwrites it.
    bf16_t* vt      = (bf16_t*)out;               // NA gemm .. na_attn

    // Tiny precomputes (independent)
    tpose_qkvw_k<<<216, 256, 0, stream>>>(qkv_w, qkv_wT);
    fold_wna_t_k<<<432, 256, 0, stream>>>(qkv_wT, na_qkv_w, Wna_t);
    fold_bna_k<<<3, 256, 0, stream>>>(qkv_b, na_qkv_w, na_qkv_b, bna);
    cpb_k<<<6, 256, 0, stream>>>(table, cpb1_w1, cpb1_b1, cpb1_w2, bt1);
    cpb_k<<<6, 256, 0, stream>>>(table, cpb2_w1, cpb2_b1, cpb2_w2, bt2);
    sigb1T_k<<<24, 256, 0, stream>>>(bt1, idx_a2w, b1pT);
    sigb_k<<<24, 256, 0, stream>>>(bt2, idx_w2a, b2p);
    tcvt_k<<<216, 256, 0, stream>>>(qkv_w, Ws_t, 192, 288, 576, 288);
    tcvt_k<<<72, 256, 0, stream>>>(na_after_w, Waft_t, 192, 96, 96, 0);
    tcvt_k<<<144, 256, 0, stream>>>(proj_w, Wproj_t, 192, 192, 192, 0);
    cvt_bf16_k<<<6144, 256, 0, stream>>>(x, xb, 65536 * 192 / 8);

    // Stripe qkv: xb @ Ws_t^T + b -> qkvs bf16 (65536,288), row-major
    mfma_gemm_k<192, 0, 3, bf16_t><<<1536, 256, 0, stream>>>(
        xb, Ws_t, qkv_b + 288, qkvs, nullptr, 192, 192, 288);

    // Folded NA qkv: xb @ Wna_t^T + bna -> Q/K planes (naqkv) + VT (vt),
    // LDS-repack coalesced epilogue
    mfma_gemm_k<192, 1, 6, bf16_t><<<3072, 256, 0, stream>>>(
        xb, Wna_t, bna, naqkv, vt, 192, 192, 576);

    // Anchor: depthwise conv (xb dead -> adw in R), pointwise GEMM -> apw
    dwconv_k<<<3072, 256, 0, stream>>>(x, adw_w, adw_b, adw);
    gemm_k<float, float><<<dim3(2, 256), 256, 0, stream>>>(
        adw, apw_w, apw_b, apw, 16384, 96, 192, 192, 96, 96);

    // Neighborhood attention (adw dead -> xna_pre in R)
    na_attn_k<<<6144, 256, 0, stream>>>(naqkv, vt, na_rpb, xna_pre);

    // na_after: xna_pre @ Waft_t^T + b -> cat[:,0:96]  (naqkv dead)
    mfma_gemm_k<192, 0, 1, bf16_t><<<512, 256, 0, stream>>>(
        xna_pre, Waft_t, na_after_b, cat, nullptr, 192, 192, 192);

    // Stripe attention -> x1, then cat[:,96:192]
    attn1_k<<<dim3(256, 6), 256, 0, stream>>>(apw, qkvs, b1pT, ls1, x1);
    attn2_k<<<1536, 256, 0, stream>>>(apw, qkvs, b2p, ls2, x1, cat);

    // Final projection: cat @ Wproj_t^T + proj_b -> out fp32 (vt dead)
    mfma_gemm_k<192, 0, 2, float><<<1024, 256, 0, stream>>>(
        cat, Wproj_t, proj_b, out, nullptr, 192, 192, 192);
}